// Round 8
// baseline (219.880 us; speedup 1.0000x reference)
//
#include <hip/hip_runtime.h>
#include <math.h>

#define N_RES 8192
#define N_IN  128
#define BATCH 16
#define LEAK  0.9f

#define NBK    128     // buckets (row>>6), 64 rows each
#define CAP1B  55296   // per-bucket capacity (avg 53248, sigma~230, +8.9 sigma)
#define CHUNK1 4096    // pass1 entries per block (2048 was 77-80us, 4096 <62us:
                       //  per-block fixed costs + e1 run length dominate)
#define CHUNK2 4096    // pass2 entries per block (32KB stg, 512 thr -> 4 blocks/CU)
#define SB2    14      // ceil(CAP1B / CHUNK2) chunks per bucket
#define TBLK   128     // transpose blocks appended to pass1 grid

// Entry encoding: y = (row << 14) | col, row 13 bits, col 14 bits (0..8319).
//   bucket = y >> 20 (row>>6); local row rr = (y >> 14) & 63; col = y & 16383.

// ws layout (bytes):
//   srcT @ 0      : [8320][16] f32 transposed state|x   (532,480)
//   bcur @ 1 MiB  : int[128]
//   z    @ 2 MiB  : [N_RES][BATCH] f32                  (524,288)
//   e1   @ 8 MiB  : uint2[NBK][CAP1B]                   (56,623,104)
// (R5: line-padding bcur falsified -- no time change, +11MB HBM writes.)
// (R6: fusing finalize into pass2 falsified -- 430us latency-stall pathology;
//  keep finalize as its own dispatch.)
#define OFF_SRCT 0
#define OFF_BCUR (1u << 20)
#define OFF_Z    (2u << 20)
#define OFF_E1   (8u << 20)
#define REQ_A    ((size_t)OFF_E1 + (size_t)NBK * CAP1B * 8)   // ~62 MiB

// ---------------------------------------------------------------------------
// K1: pass1 binning (blocks [0, nchunks)) + transpose/z-zero (blocks
// [nchunks, +TBLK)). bcur must be zeroed before launch. srcT and z are
// consumed only by pass2/finalize (next dispatches) -> no intra-kernel
// ordering needed for the transpose section. (R7: <62us at this geometry.)
__global__ __launch_bounds__(256, 4) void pass1_fused(
    const float* __restrict__ state,   // [BATCH][N_RES]
    const float* __restrict__ x,       // [BATCH][N_IN]
    const float* __restrict__ vres, const int* __restrict__ rres,
    const int* __restrict__ cres, int nres, int nbres,
    const float* __restrict__ vin, const int* __restrict__ rin,
    const int* __restrict__ cin, int nin, int nchunks,
    float* __restrict__ srcT,          // [8320][16]
    float* __restrict__ z,             // [N_RES][BATCH] (zeroed here)
    uint2* __restrict__ e1,            // [NBK][CAP1B]
    int* __restrict__ bcur) {          // [NBK] (pre-zeroed)
  int tid = threadIdx.x;

  if (blockIdx.x >= nchunks) {         // ---- transpose + z-zero section ----
    int idx0 = (blockIdx.x - nchunks) * 256 + tid;
    const int stride = TBLK * 256;
    for (int i = idx0; i < N_RES * BATCH; i += stride) {
      int b = i >> 13;
      int r = i & (N_RES - 1);
      srcT[r * BATCH + b] = state[i];
      z[i] = 0.0f;
    }
    for (int i = idx0; i < N_IN * BATCH; i += stride) {
      int b = i >> 7;
      int c = i & (N_IN - 1);
      srcT[(N_RES + c) * BATCH + b] = x[i];
    }
    return;                            // block-uniform; no barriers used here
  }

  // ---- binning section ----
  const float* vals; const int* rows; const int* cols;
  int nnz, col_off, base;
  if (blockIdx.x < nbres) {
    vals = vres; rows = rres; cols = cres; nnz = nres; col_off = 0;
    base = blockIdx.x * CHUNK1;
  } else {
    vals = vin; rows = rin; cols = cin; nnz = nin; col_off = N_RES;
    base = (blockIdx.x - nbres) * CHUNK1;
  }

  __shared__ uint2 stg[CHUNK1];              // 32 KB
  __shared__ int hist[NBK];
  __shared__ int lbase[NBK];
  __shared__ int gbase[NBK];
  __shared__ int wsum[2];
  int wave = tid >> 6, lane = tid & 63;

  if (tid < NBK) hist[tid] = 0;
  __syncthreads();

  int n = nnz - base;
  if (n > CHUNK1) n = CHUNK1;

  uint2 ent[16];
  int lp[16];
  unsigned msk = 0;
#pragma unroll
  for (int g = 0; g < 4; ++g) {
    int i0 = (g * 256 + tid) * 4;            // 16B-aligned vector offset
    if (i0 + 3 < n) {
      int4 r4 = *(const int4*)(rows + base + i0);
      int4 c4 = *(const int4*)(cols + base + i0);
      float4 v4 = *(const float4*)(vals + base + i0);
      int rr_[4] = {r4.x, r4.y, r4.z, r4.w};
      int cc_[4] = {c4.x, c4.y, c4.z, c4.w};
      float vv_[4] = {v4.x, v4.y, v4.z, v4.w};
#pragma unroll
      for (int j = 0; j < 4; ++j) {
        int e = g * 4 + j;
        ent[e] = make_uint2(__float_as_uint(vv_[j]),
                            ((unsigned)rr_[j] << 14) |
                                (unsigned)(cc_[j] + col_off));
        msk |= 1u << e;
        lp[e] = atomicAdd(&hist[rr_[j] >> 6], 1);
      }
    } else {
#pragma unroll
      for (int j = 0; j < 4; ++j) {
        int e = g * 4 + j, i = i0 + j;
        if (i < n) {
          int r = rows[base + i];
          int c = cols[base + i] + col_off;
          float v = vals[base + i];
          ent[e] = make_uint2(__float_as_uint(v),
                              ((unsigned)r << 14) | (unsigned)c);
          msk |= 1u << e;
          lp[e] = atomicAdd(&hist[r >> 6], 1);
        }
      }
    }
  }
  __syncthreads();

  int h = 0, v = 0;
  if (tid < NBK) {                           // waves 0,1 scan 128 bins
    h = hist[tid];
    v = h;
#pragma unroll
    for (int d = 1; d < 64; d <<= 1) {
      int t = __shfl_up(v, d);
      if (lane >= d) v += t;
    }
    if (lane == 63) wsum[wave] = v;
  }
  __syncthreads();
  if (tid < NBK) {
    int off = (wave == 1) ? wsum[0] : 0;
    lbase[tid] = off + v - h;
    gbase[tid] = h ? atomicAdd(&bcur[tid], h) : 0;
  }
  __syncthreads();
#pragma unroll
  for (int e = 0; e < 16; ++e) {
    if (msk & (1u << e)) {
      int b = (int)(ent[e].y >> 20);         // recompute bin from packed row
      stg[lbase[b] + lp[e]] = ent[e];
    }
  }
  __syncthreads();
  for (int i = tid; i < n; i += 256) {
    uint2 ld = stg[i];
    int b = (int)(ld.y >> 20);
    int p = gbase[b] + (i - lbase[b]);
    if (p < CAP1B) e1[(size_t)b * CAP1B + p] = ld;
  }
}

// ---------------------------------------------------------------------------
// K2: sort-by-local-row (LDS int atomics = native ds_add_rtn_u32) then
// conflict-free register accumulation + shuffle reduce. NO FP LDS atomics
// (R1/R2: CAS retry loop, 568us). NO fused finalize (R6: 430us pathology).
// R8: inner loop explicitly software-pipelined 3-stage (entry ds_read 2
// steps ahead, srcT line 1 step ahead, clamp+mask instead of divergent
// guard). R7 counters showed latency-bound: VALUBusy 24%, HBM 12%, VGPR 20
// (compiler left the chain ds_read->addr->L2-load->FMA fully exposed).
// 512 threads, 8 waves, 33KB LDS -> 4 blocks/CU = 32 waves/CU. Epilogue:
// global unsafeAtomicAdd (HW global_atomic_add_f32) into z[8192][16],
// L2-resident. Grid: (SB2, NBK).
__global__ __launch_bounds__(512, 8) void pass2_accum(
    const uint2* __restrict__ e1,
    const int* __restrict__ bcur,
    const float* __restrict__ srcT,     // [8320][16]
    float* __restrict__ z) {            // [N_RES][BATCH] (pre-zeroed)
  int bucket = blockIdx.y;
  int ch = blockIdx.x;
  int tid = threadIdx.x;

  int cnt = bcur[bucket];
  if (cnt > CAP1B) cnt = CAP1B;
  int base = ch * CHUNK2;
  if (base >= cnt) return;              // block-uniform early exit
  int n = cnt - base;
  if (n > CHUNK2) n = CHUNK2;

  __shared__ uint2 stg[CHUNK2];         // 32 KB
  __shared__ int hist[64];
  __shared__ int sbase[65];
  int wave = tid >> 6, lane = tid & 63;
  if (tid < 64) hist[tid] = 0;
  __syncthreads();

  const uint2* __restrict__ src = e1 + (size_t)bucket * CAP1B + base;
  uint2 ent[8];
  int lp[8];
  unsigned msk = 0;
#pragma unroll
  for (int g = 0; g < 4; ++g) {
    int i = (g * 512 + tid) * 2;        // paired entries, 16B aligned
    int e = g * 2;
    if (i + 1 < n) {
      uint4 q = *(const uint4*)(src + i);
      ent[e]     = make_uint2(q.x, q.y);
      ent[e + 1] = make_uint2(q.z, q.w);
      msk |= 3u << e;
      lp[e]     = atomicAdd(&hist[(ent[e].y >> 14) & 63u], 1);
      lp[e + 1] = atomicAdd(&hist[(ent[e + 1].y >> 14) & 63u], 1);
    } else if (i < n) {
      ent[e] = src[i];
      msk |= 1u << e;
      lp[e] = atomicAdd(&hist[(ent[e].y >> 14) & 63u], 1);
    }
  }
  __syncthreads();
  if (tid < 64) {                       // one wave: 64-bin exclusive scan
    int hh = hist[tid];
    int vv = hh;
#pragma unroll
    for (int d = 1; d < 64; d <<= 1) {
      int t = __shfl_up(vv, d);
      if (lane >= d) vv += t;
    }
    sbase[tid] = vv - hh;
    if (tid == 63) sbase[64] = vv;
  }
  __syncthreads();
#pragma unroll
  for (int e = 0; e < 8; ++e)
    if (msk & (1u << e))
      stg[sbase[(ent[e].y >> 14) & 63u] + lp[e]] = ent[e];
  __syncthreads();

  // Accumulation: wave handles rows wave*8..+7. Per step, 16 entries:
  // 4-lane group (eoff = lane>>2) broadcasts one stg entry and reads one
  // 16B slice (bq = lane&3) of the 64B srcT line; FMA into float4; then
  // shfl_xor{4,8,16,32} reduce; lanes 0..3 -> 16 contiguous global fadds.
  // 3-stage pipeline: eeN = entry for step i+1 (ds_read issued 2 steps
  // early incl. prologue), sC = srcT line for step i (issued 1 step early).
  // Out-of-segment slots clamp to the segment's last entry (valid row data)
  // with vv masked to 0 -> bit-identical sums, no divergent branch.
  int eoff = lane >> 2;
  int bq = lane & 3;
  const float4* __restrict__ s4 = (const float4*)srcT;

  for (int rr = wave * 8; rr < wave * 8 + 8; ++rr) {
    int s0 = sbase[rr], s1 = sbase[rr + 1];
    float4 acc = make_float4(0.f, 0.f, 0.f, 0.f);
    if (s0 < s1) {
      // prologue: entry+line for step 0, entry for step 1
      int e0 = s0 + eoff;
      int c0 = (e0 < s1) ? e0 : s1 - 1;
      uint2 eeC = stg[c0];
      float vvC = (e0 < s1) ? __uint_as_float(eeC.x) : 0.0f;
      float4 sC = s4[(int)(eeC.y & 16383u) * 4 + bq];
      int e1i = s0 + 16 + eoff;
      int c1 = (e1i < s1) ? e1i : s1 - 1;
      uint2 eeN = stg[c1];
      float vvN = (e1i < s1) ? __uint_as_float(eeN.x) : 0.0f;
      for (int i0 = s0; i0 < s1; i0 += 16) {
        // issue step i+2's entry read and step i+1's line read first
        int e2 = i0 + 32 + eoff;
        int c2 = (e2 < s1) ? e2 : s1 - 1;
        uint2 ee2 = stg[c2];
        float vv2 = (e2 < s1) ? __uint_as_float(ee2.x) : 0.0f;
        float4 sN = s4[(int)(eeN.y & 16383u) * 4 + bq];
        // FMA for step i (loads issued >=1 full step earlier)
        acc.x += vvC * sC.x;
        acc.y += vvC * sC.y;
        acc.z += vvC * sC.z;
        acc.w += vvC * sC.w;
        eeC = eeN; vvC = vvN; sC = sN;
        eeN = ee2; vvN = vv2;
      }
    }
#pragma unroll
    for (int m = 4; m <= 32; m <<= 1) {
      acc.x += __shfl_xor(acc.x, m);
      acc.y += __shfl_xor(acc.y, m);
      acc.z += __shfl_xor(acc.z, m);
      acc.w += __shfl_xor(acc.w, m);
    }
    if (lane < 4) {                     // lane == bq 0..3
      float* zp = z + (size_t)(bucket * 64 + rr) * BATCH + lane * 4;
      unsafeAtomicAdd(zp + 0, acc.x);
      unsafeAtomicAdd(zp + 1, acc.y);
      unsafeAtomicAdd(zp + 2, acc.z);
      unsafeAtomicAdd(zp + 3, acc.w);
    }
  }
}

// ---------------------------------------------------------------------------
__global__ __launch_bounds__(256) void finalize_z(
    const float* __restrict__ z, const float* __restrict__ state,
    const float* __restrict__ res_bias, const float* __restrict__ in_bias,
    float* __restrict__ out) {
  int tid = blockIdx.x * 256 + threadIdx.x;
  if (tid >= BATCH * N_RES) return;
  int b = tid >> 13;
  int r = tid & (N_RES - 1);
  float zz = z[r * 16 + b] + res_bias[r] + in_bias[r];
  out[tid] = (1.0f - LEAK) * state[tid] + LEAK * erff(zz);
}

// ---------------------------------------------------------------------------
// Fallback (small ws): atomic path, correct but slow.
__global__ __launch_bounds__(256) void transpose_nb(
    const float* __restrict__ state, const float* __restrict__ x,
    float* __restrict__ srcT) {
  int tid = blockIdx.x * 256 + threadIdx.x;
  if (tid < N_RES * BATCH) {
    int b = tid >> 13;
    int r = tid & (N_RES - 1);
    srcT[r * BATCH + b] = state[tid];
  }
  if (tid < N_IN * BATCH) {
    int b = tid >> 7;
    int c = tid & (N_IN - 1);
    srcT[(N_RES + c) * BATCH + b] = x[tid];
  }
}

__global__ __launch_bounds__(256) void spmm_atomic(
    const float* __restrict__ vals, const int* __restrict__ rows,
    const int* __restrict__ cols, const float* __restrict__ srcT,
    int col_off, float* __restrict__ zz, int nnz) {
  int i = blockIdx.x * blockDim.x + threadIdx.x;
  if (i >= nnz) return;
  float v = vals[i];
  int r = rows[i];
  int c = cols[i] + col_off;
  const float4* __restrict__ sp = (const float4*)(srcT + c * BATCH);
  float* zr = zz + r * BATCH;
#pragma unroll
  for (int qq = 0; qq < 4; ++qq) {
    float4 s = sp[qq];
    unsafeAtomicAdd(zr + qq * 4 + 0, v * s.x);
    unsafeAtomicAdd(zr + qq * 4 + 1, v * s.y);
    unsafeAtomicAdd(zr + qq * 4 + 2, v * s.z);
    unsafeAtomicAdd(zr + qq * 4 + 3, v * s.w);
  }
}

// ---------------------------------------------------------------------------
extern "C" void kernel_launch(void* const* d_in, const int* in_sizes, int n_in,
                              void* d_out, int out_size, void* d_ws, size_t ws_size,
                              hipStream_t stream) {
  const float* state    = (const float*)d_in[0];
  const float* x        = (const float*)d_in[1];
  const float* res_vals = (const float*)d_in[2];
  const int*   res_rows = (const int*)d_in[3];
  const int*   res_cols = (const int*)d_in[4];
  const float* res_bias = (const float*)d_in[5];
  const float* in_vals  = (const float*)d_in[6];
  const int*   in_rows  = (const int*)d_in[7];
  const int*   in_cols  = (const int*)d_in[8];
  const float* in_bias  = (const float*)d_in[9];

  const int res_nnz = in_sizes[2];
  const int in_nnz  = in_sizes[6];

  char* ws = (char*)d_ws;
  float* srcT = (float*)(ws + OFF_SRCT);
  float* z    = (float*)(ws + OFF_Z);
  float* out = (float*)d_out;

  if (ws_size >= REQ_A) {
    int* bcur = (int*)(ws + OFF_BCUR);
    uint2* e1 = (uint2*)(ws + OFF_E1);
    int nbres = (res_nnz + CHUNK1 - 1) / CHUNK1;
    int nbin  = (in_nnz + CHUNK1 - 1) / CHUNK1;
    int nchunks = nbres + nbin;

    hipMemsetAsync(bcur, 0, NBK * sizeof(int), stream);

    pass1_fused<<<nchunks + TBLK, 256, 0, stream>>>(
        state, x, res_vals, res_rows, res_cols, res_nnz, nbres,
        in_vals, in_rows, in_cols, in_nnz, nchunks, srcT, z, e1, bcur);

    pass2_accum<<<dim3(SB2, NBK), 512, 0, stream>>>(e1, bcur, srcT, z);

    finalize_z<<<512, 256, 0, stream>>>(z, state, res_bias, in_bias, out);
  } else {
    hipMemsetAsync(z, 0, N_RES * BATCH * sizeof(float), stream);
    transpose_nb<<<512, 256, 0, stream>>>(state, x, srcT);
    spmm_atomic<<<(res_nnz + 255) / 256, 256, 0, stream>>>(
        res_vals, res_rows, res_cols, srcT, 0, z, res_nnz);
    spmm_atomic<<<(in_nnz + 255) / 256, 256, 0, stream>>>(
        in_vals, in_rows, in_cols, srcT, N_RES, z, in_nnz);
    finalize_z<<<512, 256, 0, stream>>>(z, state, res_bias, in_bias, out);
  }
}

// Round 9
// 212.408 us; speedup vs baseline: 1.0352x; 1.0352x over previous
//
#include <hip/hip_runtime.h>
#include <math.h>

#define N_RES 8192
#define N_IN  128
#define BATCH 16
#define LEAK  0.9f

#define NBK    128     // buckets (row>>6), 64 rows each
#define CAP1B  55296   // per-bucket capacity (avg 53248, sigma~230, +8.9 sigma)
#define CHUNK1 4096    // pass1 entries per block (2048 was 77-80us, 4096 <62us:
                       //  per-block fixed costs + e1 run length dominate)
#define CHUNK2 4096    // pass2 entries per block (32KB stg, 512 thr -> 4 blocks/CU)
#define SB2    14      // ceil(CAP1B / CHUNK2) chunks per bucket
#define TBLK   128     // transpose blocks appended to pass1 grid

// Entry encoding: y = (row << 14) | col, row 13 bits, col 14 bits (0..8319).
//   bucket = y >> 20 (row>>6); local row rr = (y >> 14) & 63; col = y & 16383.

// ws layout (bytes):
//   srcT @ 0      : [8320][16] f32 transposed state|x   (532,480)
//   bcur @ 1 MiB  : int[128]
//   z    @ 2 MiB  : [N_RES][BATCH] f32                  (524,288)
//   e1   @ 8 MiB  : uint2[NBK][CAP1B]                   (56,623,104)
// Falsified levers (do not retry):
//  R1/R2: FP atomicAdd/unsafeAtomicAdd on LDS -> CAS retry loop, 568us.
//  R5: line-padding bcur -> no change, +11MB HBM writes.
//  R6: fusing finalize into pass2 -> 430us latency pathology.
//  R8: predicated (clamp+mask) software pipeline -> +30% VALU, compiler
//      re-serialized (VGPR stayed 20), 66us vs 62us.
#define OFF_SRCT 0
#define OFF_BCUR (1u << 20)
#define OFF_Z    (2u << 20)
#define OFF_E1   (8u << 20)
#define REQ_A    ((size_t)OFF_E1 + (size_t)NBK * CAP1B * 8)   // ~62 MiB

// ---------------------------------------------------------------------------
// K1: pass1 binning (blocks [0, nchunks)) + transpose/z-zero (blocks
// [nchunks, +TBLK)). bcur must be zeroed before launch. srcT and z are
// consumed only by pass2/finalize (next dispatches) -> no intra-kernel
// ordering needed for the transpose section. (R7: <62us at this geometry.)
__global__ __launch_bounds__(256, 4) void pass1_fused(
    const float* __restrict__ state,   // [BATCH][N_RES]
    const float* __restrict__ x,       // [BATCH][N_IN]
    const float* __restrict__ vres, const int* __restrict__ rres,
    const int* __restrict__ cres, int nres, int nbres,
    const float* __restrict__ vin, const int* __restrict__ rin,
    const int* __restrict__ cin, int nin, int nchunks,
    float* __restrict__ srcT,          // [8320][16]
    float* __restrict__ z,             // [N_RES][BATCH] (zeroed here)
    uint2* __restrict__ e1,            // [NBK][CAP1B]
    int* __restrict__ bcur) {          // [NBK] (pre-zeroed)
  int tid = threadIdx.x;

  if (blockIdx.x >= nchunks) {         // ---- transpose + z-zero section ----
    int idx0 = (blockIdx.x - nchunks) * 256 + tid;
    const int stride = TBLK * 256;
    for (int i = idx0; i < N_RES * BATCH; i += stride) {
      int b = i >> 13;
      int r = i & (N_RES - 1);
      srcT[r * BATCH + b] = state[i];
      z[i] = 0.0f;
    }
    for (int i = idx0; i < N_IN * BATCH; i += stride) {
      int b = i >> 7;
      int c = i & (N_IN - 1);
      srcT[(N_RES + c) * BATCH + b] = x[i];
    }
    return;                            // block-uniform; no barriers used here
  }

  // ---- binning section ----
  const float* vals; const int* rows; const int* cols;
  int nnz, col_off, base;
  if (blockIdx.x < nbres) {
    vals = vres; rows = rres; cols = cres; nnz = nres; col_off = 0;
    base = blockIdx.x * CHUNK1;
  } else {
    vals = vin; rows = rin; cols = cin; nnz = nin; col_off = N_RES;
    base = (blockIdx.x - nbres) * CHUNK1;
  }

  __shared__ uint2 stg[CHUNK1];              // 32 KB
  __shared__ int hist[NBK];
  __shared__ int lbase[NBK];
  __shared__ int gbase[NBK];
  __shared__ int wsum[2];
  int wave = tid >> 6, lane = tid & 63;

  if (tid < NBK) hist[tid] = 0;
  __syncthreads();

  int n = nnz - base;
  if (n > CHUNK1) n = CHUNK1;

  uint2 ent[16];
  int lp[16];
  unsigned msk = 0;
#pragma unroll
  for (int g = 0; g < 4; ++g) {
    int i0 = (g * 256 + tid) * 4;            // 16B-aligned vector offset
    if (i0 + 3 < n) {
      int4 r4 = *(const int4*)(rows + base + i0);
      int4 c4 = *(const int4*)(cols + base + i0);
      float4 v4 = *(const float4*)(vals + base + i0);
      int rr_[4] = {r4.x, r4.y, r4.z, r4.w};
      int cc_[4] = {c4.x, c4.y, c4.z, c4.w};
      float vv_[4] = {v4.x, v4.y, v4.z, v4.w};
#pragma unroll
      for (int j = 0; j < 4; ++j) {
        int e = g * 4 + j;
        ent[e] = make_uint2(__float_as_uint(vv_[j]),
                            ((unsigned)rr_[j] << 14) |
                                (unsigned)(cc_[j] + col_off));
        msk |= 1u << e;
        lp[e] = atomicAdd(&hist[rr_[j] >> 6], 1);
      }
    } else {
#pragma unroll
      for (int j = 0; j < 4; ++j) {
        int e = g * 4 + j, i = i0 + j;
        if (i < n) {
          int r = rows[base + i];
          int c = cols[base + i] + col_off;
          float v = vals[base + i];
          ent[e] = make_uint2(__float_as_uint(v),
                              ((unsigned)r << 14) | (unsigned)c);
          msk |= 1u << e;
          lp[e] = atomicAdd(&hist[r >> 6], 1);
        }
      }
    }
  }
  __syncthreads();

  int h = 0, v = 0;
  if (tid < NBK) {                           // waves 0,1 scan 128 bins
    h = hist[tid];
    v = h;
#pragma unroll
    for (int d = 1; d < 64; d <<= 1) {
      int t = __shfl_up(v, d);
      if (lane >= d) v += t;
    }
    if (lane == 63) wsum[wave] = v;
  }
  __syncthreads();
  if (tid < NBK) {
    int off = (wave == 1) ? wsum[0] : 0;
    lbase[tid] = off + v - h;
    gbase[tid] = h ? atomicAdd(&bcur[tid], h) : 0;
  }
  __syncthreads();
#pragma unroll
  for (int e = 0; e < 16; ++e) {
    if (msk & (1u << e)) {
      int b = (int)(ent[e].y >> 20);         // recompute bin from packed row
      stg[lbase[b] + lp[e]] = ent[e];
    }
  }
  __syncthreads();
  for (int i = tid; i < n; i += 256) {
    uint2 ld = stg[i];
    int b = (int)(ld.y >> 20);
    int p = gbase[b] + (i - lbase[b]);
    if (p < CAP1B) e1[(size_t)b * CAP1B + p] = ld;
  }
}

// ---------------------------------------------------------------------------
// K2: sort-by-local-row (LDS int atomics = native ds_add_rtn_u32) then
// conflict-free register accumulation + shuffle reduce. R9 accumulate loop:
// BRANCH-FREE 32-entry main step (two independent unconditional chains ->
// compiler can co-issue both ds_reads + both srcT loads, MLP=2, zero
// predication VALU), then one unconditional 16-step, then guarded <=16 tail.
// (R8's predicated pipeline falsified: +30% VALU, compiler re-serialized.)
// 512 threads, 8 waves, 33KB LDS -> 4 blocks/CU = 32 waves/CU. Epilogue:
// global unsafeAtomicAdd (HW global_atomic_add_f32) into z[8192][16],
// L2-resident. Grid: (SB2, NBK).
__global__ __launch_bounds__(512, 8) void pass2_accum(
    const uint2* __restrict__ e1,
    const int* __restrict__ bcur,
    const float* __restrict__ srcT,     // [8320][16]
    float* __restrict__ z) {            // [N_RES][BATCH] (pre-zeroed)
  int bucket = blockIdx.y;
  int ch = blockIdx.x;
  int tid = threadIdx.x;

  int cnt = bcur[bucket];
  if (cnt > CAP1B) cnt = CAP1B;
  int base = ch * CHUNK2;
  if (base >= cnt) return;              // block-uniform early exit
  int n = cnt - base;
  if (n > CHUNK2) n = CHUNK2;

  __shared__ uint2 stg[CHUNK2];         // 32 KB
  __shared__ int hist[64];
  __shared__ int sbase[65];
  int wave = tid >> 6, lane = tid & 63;
  if (tid < 64) hist[tid] = 0;
  __syncthreads();

  const uint2* __restrict__ src = e1 + (size_t)bucket * CAP1B + base;
  uint2 ent[8];
  int lp[8];
  unsigned msk = 0;
#pragma unroll
  for (int g = 0; g < 4; ++g) {
    int i = (g * 512 + tid) * 2;        // paired entries, 16B aligned
    int e = g * 2;
    if (i + 1 < n) {
      uint4 q = *(const uint4*)(src + i);
      ent[e]     = make_uint2(q.x, q.y);
      ent[e + 1] = make_uint2(q.z, q.w);
      msk |= 3u << e;
      lp[e]     = atomicAdd(&hist[(ent[e].y >> 14) & 63u], 1);
      lp[e + 1] = atomicAdd(&hist[(ent[e + 1].y >> 14) & 63u], 1);
    } else if (i < n) {
      ent[e] = src[i];
      msk |= 1u << e;
      lp[e] = atomicAdd(&hist[(ent[e].y >> 14) & 63u], 1);
    }
  }
  __syncthreads();
  if (tid < 64) {                       // one wave: 64-bin exclusive scan
    int hh = hist[tid];
    int vv = hh;
#pragma unroll
    for (int d = 1; d < 64; d <<= 1) {
      int t = __shfl_up(vv, d);
      if (lane >= d) vv += t;
    }
    sbase[tid] = vv - hh;
    if (tid == 63) sbase[64] = vv;
  }
  __syncthreads();
#pragma unroll
  for (int e = 0; e < 8; ++e)
    if (msk & (1u << e))
      stg[sbase[(ent[e].y >> 14) & 63u] + lp[e]] = ent[e];
  __syncthreads();

  // Accumulation: wave handles rows wave*8..+7. 4-lane group (eoff=lane>>2)
  // broadcasts one stg entry and reads one 16B slice (bq=lane&3) of the 64B
  // srcT line; FMA into float4; shfl_xor{4,8,16,32} reduce; lanes 0..3 ->
  // 16 contiguous global fadds. Main loop is wave-uniform and branch-free.
  int eoff = lane >> 2;
  int bq = lane & 3;
  const float4* __restrict__ s4 = (const float4*)srcT;

  for (int rr = wave * 8; rr < wave * 8 + 8; ++rr) {
    int s0 = sbase[rr], s1 = sbase[rr + 1];
    float4 acc = make_float4(0.f, 0.f, 0.f, 0.f);
    int i0 = s0;
    // 32-entry steps: two independent unconditional chains (MLP=2).
    for (; i0 + 32 <= s1; i0 += 32) {
      uint2 eA = stg[i0 + eoff];
      uint2 eB = stg[i0 + 16 + eoff];
      float4 sA = s4[(int)(eA.y & 16383u) * 4 + bq];
      float4 sB = s4[(int)(eB.y & 16383u) * 4 + bq];
      float vA = __uint_as_float(eA.x);
      float vB = __uint_as_float(eB.x);
      acc.x += vA * sA.x;
      acc.y += vA * sA.y;
      acc.z += vA * sA.z;
      acc.w += vA * sA.w;
      acc.x += vB * sB.x;
      acc.y += vB * sB.y;
      acc.z += vB * sB.z;
      acc.w += vB * sB.w;
    }
    // one unconditional 16-step (wave-uniform test)
    if (i0 + 16 <= s1) {
      uint2 eA = stg[i0 + eoff];
      float4 sA = s4[(int)(eA.y & 16383u) * 4 + bq];
      float vA = __uint_as_float(eA.x);
      acc.x += vA * sA.x;
      acc.y += vA * sA.y;
      acc.z += vA * sA.z;
      acc.w += vA * sA.w;
      i0 += 16;
    }
    // guarded tail (<16 entries, divergent only here)
    if (i0 < s1) {
      int e = i0 + eoff;
      if (e < s1) {
        uint2 eA = stg[e];
        float4 sA = s4[(int)(eA.y & 16383u) * 4 + bq];
        float vA = __uint_as_float(eA.x);
        acc.x += vA * sA.x;
        acc.y += vA * sA.y;
        acc.z += vA * sA.z;
        acc.w += vA * sA.w;
      }
    }
#pragma unroll
    for (int m = 4; m <= 32; m <<= 1) {
      acc.x += __shfl_xor(acc.x, m);
      acc.y += __shfl_xor(acc.y, m);
      acc.z += __shfl_xor(acc.z, m);
      acc.w += __shfl_xor(acc.w, m);
    }
    if (lane < 4) {                     // lane == bq 0..3
      float* zp = z + (size_t)(bucket * 64 + rr) * BATCH + lane * 4;
      unsafeAtomicAdd(zp + 0, acc.x);
      unsafeAtomicAdd(zp + 1, acc.y);
      unsafeAtomicAdd(zp + 2, acc.z);
      unsafeAtomicAdd(zp + 3, acc.w);
    }
  }
}

// ---------------------------------------------------------------------------
__global__ __launch_bounds__(256) void finalize_z(
    const float* __restrict__ z, const float* __restrict__ state,
    const float* __restrict__ res_bias, const float* __restrict__ in_bias,
    float* __restrict__ out) {
  int tid = blockIdx.x * 256 + threadIdx.x;
  if (tid >= BATCH * N_RES) return;
  int b = tid >> 13;
  int r = tid & (N_RES - 1);
  float zz = z[r * 16 + b] + res_bias[r] + in_bias[r];
  out[tid] = (1.0f - LEAK) * state[tid] + LEAK * erff(zz);
}

// ---------------------------------------------------------------------------
// Fallback (small ws): atomic path, correct but slow.
__global__ __launch_bounds__(256) void transpose_nb(
    const float* __restrict__ state, const float* __restrict__ x,
    float* __restrict__ srcT) {
  int tid = blockIdx.x * 256 + threadIdx.x;
  if (tid < N_RES * BATCH) {
    int b = tid >> 13;
    int r = tid & (N_RES - 1);
    srcT[r * BATCH + b] = state[tid];
  }
  if (tid < N_IN * BATCH) {
    int b = tid >> 7;
    int c = tid & (N_IN - 1);
    srcT[(N_RES + c) * BATCH + b] = x[tid];
  }
}

__global__ __launch_bounds__(256) void spmm_atomic(
    const float* __restrict__ vals, const int* __restrict__ rows,
    const int* __restrict__ cols, const float* __restrict__ srcT,
    int col_off, float* __restrict__ zz, int nnz) {
  int i = blockIdx.x * blockDim.x + threadIdx.x;
  if (i >= nnz) return;
  float v = vals[i];
  int r = rows[i];
  int c = cols[i] + col_off;
  const float4* __restrict__ sp = (const float4*)(srcT + c * BATCH);
  float* zr = zz + r * BATCH;
#pragma unroll
  for (int qq = 0; qq < 4; ++qq) {
    float4 s = sp[qq];
    unsafeAtomicAdd(zr + qq * 4 + 0, v * s.x);
    unsafeAtomicAdd(zr + qq * 4 + 1, v * s.y);
    unsafeAtomicAdd(zr + qq * 4 + 2, v * s.z);
    unsafeAtomicAdd(zr + qq * 4 + 3, v * s.w);
  }
}

// ---------------------------------------------------------------------------
extern "C" void kernel_launch(void* const* d_in, const int* in_sizes, int n_in,
                              void* d_out, int out_size, void* d_ws, size_t ws_size,
                              hipStream_t stream) {
  const float* state    = (const float*)d_in[0];
  const float* x        = (const float*)d_in[1];
  const float* res_vals = (const float*)d_in[2];
  const int*   res_rows = (const int*)d_in[3];
  const int*   res_cols = (const int*)d_in[4];
  const float* res_bias = (const float*)d_in[5];
  const float* in_vals  = (const float*)d_in[6];
  const int*   in_rows  = (const int*)d_in[7];
  const int*   in_cols  = (const int*)d_in[8];
  const float* in_bias  = (const float*)d_in[9];

  const int res_nnz = in_sizes[2];
  const int in_nnz  = in_sizes[6];

  char* ws = (char*)d_ws;
  float* srcT = (float*)(ws + OFF_SRCT);
  float* z    = (float*)(ws + OFF_Z);
  float* out = (float*)d_out;

  if (ws_size >= REQ_A) {
    int* bcur = (int*)(ws + OFF_BCUR);
    uint2* e1 = (uint2*)(ws + OFF_E1);
    int nbres = (res_nnz + CHUNK1 - 1) / CHUNK1;
    int nbin  = (in_nnz + CHUNK1 - 1) / CHUNK1;
    int nchunks = nbres + nbin;

    hipMemsetAsync(bcur, 0, NBK * sizeof(int), stream);

    pass1_fused<<<nchunks + TBLK, 256, 0, stream>>>(
        state, x, res_vals, res_rows, res_cols, res_nnz, nbres,
        in_vals, in_rows, in_cols, in_nnz, nchunks, srcT, z, e1, bcur);

    pass2_accum<<<dim3(SB2, NBK), 512, 0, stream>>>(e1, bcur, srcT, z);

    finalize_z<<<512, 256, 0, stream>>>(z, state, res_bias, in_bias, out);
  } else {
    hipMemsetAsync(z, 0, N_RES * BATCH * sizeof(float), stream);
    transpose_nb<<<512, 256, 0, stream>>>(state, x, srcT);
    spmm_atomic<<<(res_nnz + 255) / 256, 256, 0, stream>>>(
        res_vals, res_rows, res_cols, srcT, 0, z, res_nnz);
    spmm_atomic<<<(in_nnz + 255) / 256, 256, 0, stream>>>(
        in_vals, in_rows, in_cols, srcT, N_RES, z, in_nnz);
    finalize_z<<<512, 256, 0, stream>>>(z, state, res_bias, in_bias, out);
  }
}

// Round 10
// 201.965 us; speedup vs baseline: 1.0887x; 1.0517x over previous
//
#include <hip/hip_runtime.h>
#include <math.h>

#define N_RES 8192
#define N_IN  128
#define BATCH 16
#define LEAK  0.9f

#define NBK    128     // buckets (row>>6), 64 rows each
#define CAP1B  55296   // per-bucket capacity (avg 53248, sigma~230, +8.9 sigma)
#define CHUNK1 8192    // pass1 entries per block (trend: 2048->77us, 4096->60us;
                       //  fixed costs per block + e1 run length dominate)
#define CHUNK2 4096    // pass2 entries per block (32KB stg, 512 thr -> 4 blocks/CU)
#define SB2    14      // ceil(CAP1B / CHUNK2) chunks per bucket
#define TBLK   128     // transpose blocks appended to pass1 grid

// Entry encoding: y = (row << 14) | col, row 13 bits, col 14 bits (0..8319).
//   bucket = y >> 20 (row>>6); local row rr = (y >> 14) & 63; col = y & 16383.

// ws layout (bytes):
//   srcT @ 0      : [8320][16] f32 transposed state|x   (532,480)
//   bcur @ 1 MiB  : int[128]
//   z    @ 2 MiB  : [N_RES][BATCH] f32                  (524,288)
//   e1   @ 8 MiB  : uint2[NBK][CAP1B]                   (56,623,104)
// Falsified levers (do not retry):
//  R1/R2: FP atomicAdd/unsafeAtomicAdd on LDS -> CAS retry loop, 568us.
//  R5: line-padding bcur -> no change, +11MB HBM writes.
//  R6: fusing finalize into pass2 -> 430us latency pathology.
//  R8: predicated (clamp+mask) software pipeline -> +30% VALU, compiler
//      re-serialized (VGPR stayed 20), 66us vs 62us.
//  R9: branch-free 32-step helped (62->58) but VGPR stayed 20: compiler
//      still reused regs across the two srcT loads (no real MLP).
#define OFF_SRCT 0
#define OFF_BCUR (1u << 20)
#define OFF_Z    (2u << 20)
#define OFF_E1   (8u << 20)
#define REQ_A    ((size_t)OFF_E1 + (size_t)NBK * CAP1B * 8)   // ~62 MiB

// ---------------------------------------------------------------------------
// K1: pass1 binning (blocks [0, nchunks)) + transpose/z-zero (blocks
// [nchunks, +TBLK)). bcur must be zeroed before launch. srcT and z are
// consumed only by pass2/finalize (next dispatches) -> no intra-kernel
// ordering needed for the transpose section. 512 threads, CHUNK1=8192:
// 64KB stg -> 2 blocks/CU x 8 waves = 16 waves/CU (same residency as the
// 4096/256thr version -> isolates the per-block-fixed-cost variable).
__global__ __launch_bounds__(512, 4) void pass1_fused(
    const float* __restrict__ state,   // [BATCH][N_RES]
    const float* __restrict__ x,       // [BATCH][N_IN]
    const float* __restrict__ vres, const int* __restrict__ rres,
    const int* __restrict__ cres, int nres, int nbres,
    const float* __restrict__ vin, const int* __restrict__ rin,
    const int* __restrict__ cin, int nin, int nchunks,
    float* __restrict__ srcT,          // [8320][16]
    float* __restrict__ z,             // [N_RES][BATCH] (zeroed here)
    uint2* __restrict__ e1,            // [NBK][CAP1B]
    int* __restrict__ bcur) {          // [NBK] (pre-zeroed)
  int tid = threadIdx.x;

  if (blockIdx.x >= nchunks) {         // ---- transpose + z-zero section ----
    int idx0 = (blockIdx.x - nchunks) * 512 + tid;
    const int stride = TBLK * 512;
    for (int i = idx0; i < N_RES * BATCH; i += stride) {
      int b = i >> 13;
      int r = i & (N_RES - 1);
      srcT[r * BATCH + b] = state[i];
      z[i] = 0.0f;
    }
    for (int i = idx0; i < N_IN * BATCH; i += stride) {
      int b = i >> 7;
      int c = i & (N_IN - 1);
      srcT[(N_RES + c) * BATCH + b] = x[i];
    }
    return;                            // block-uniform; no barriers used here
  }

  // ---- binning section ----
  const float* vals; const int* rows; const int* cols;
  int nnz, col_off, base;
  if (blockIdx.x < nbres) {
    vals = vres; rows = rres; cols = cres; nnz = nres; col_off = 0;
    base = blockIdx.x * CHUNK1;
  } else {
    vals = vin; rows = rin; cols = cin; nnz = nin; col_off = N_RES;
    base = (blockIdx.x - nbres) * CHUNK1;
  }

  __shared__ uint2 stg[CHUNK1];              // 64 KB
  __shared__ int hist[NBK];
  __shared__ int lbase[NBK];
  __shared__ int gbase[NBK];
  __shared__ int wsum[2];
  int wave = tid >> 6, lane = tid & 63;

  if (tid < NBK) hist[tid] = 0;
  __syncthreads();

  int n = nnz - base;
  if (n > CHUNK1) n = CHUNK1;

  uint2 ent[16];
  int lp[16];
  unsigned msk = 0;
#pragma unroll
  for (int g = 0; g < 4; ++g) {
    int i0 = (g * 512 + tid) * 4;            // 16B-aligned vector offset
    if (i0 + 3 < n) {
      int4 r4 = *(const int4*)(rows + base + i0);
      int4 c4 = *(const int4*)(cols + base + i0);
      float4 v4 = *(const float4*)(vals + base + i0);
      int rr_[4] = {r4.x, r4.y, r4.z, r4.w};
      int cc_[4] = {c4.x, c4.y, c4.z, c4.w};
      float vv_[4] = {v4.x, v4.y, v4.z, v4.w};
#pragma unroll
      for (int j = 0; j < 4; ++j) {
        int e = g * 4 + j;
        ent[e] = make_uint2(__float_as_uint(vv_[j]),
                            ((unsigned)rr_[j] << 14) |
                                (unsigned)(cc_[j] + col_off));
        msk |= 1u << e;
        lp[e] = atomicAdd(&hist[rr_[j] >> 6], 1);
      }
    } else {
#pragma unroll
      for (int j = 0; j < 4; ++j) {
        int e = g * 4 + j, i = i0 + j;
        if (i < n) {
          int r = rows[base + i];
          int c = cols[base + i] + col_off;
          float v = vals[base + i];
          ent[e] = make_uint2(__float_as_uint(v),
                              ((unsigned)r << 14) | (unsigned)c);
          msk |= 1u << e;
          lp[e] = atomicAdd(&hist[r >> 6], 1);
        }
      }
    }
  }
  __syncthreads();

  int h = 0, v = 0;
  if (tid < NBK) {                           // waves 0,1 scan 128 bins
    h = hist[tid];
    v = h;
#pragma unroll
    for (int d = 1; d < 64; d <<= 1) {
      int t = __shfl_up(v, d);
      if (lane >= d) v += t;
    }
    if (lane == 63) wsum[wave] = v;
  }
  __syncthreads();
  if (tid < NBK) {
    int off = (wave == 1) ? wsum[0] : 0;
    lbase[tid] = off + v - h;
    gbase[tid] = h ? atomicAdd(&bcur[tid], h) : 0;
  }
  __syncthreads();
#pragma unroll
  for (int e = 0; e < 16; ++e) {
    if (msk & (1u << e)) {
      int b = (int)(ent[e].y >> 20);         // recompute bin from packed row
      stg[lbase[b] + lp[e]] = ent[e];
    }
  }
  __syncthreads();
  for (int i = tid; i < n; i += 512) {
    uint2 ld = stg[i];
    int b = (int)(ld.y >> 20);
    int p = gbase[b] + (i - lbase[b]);
    if (p < CAP1B) e1[(size_t)b * CAP1B + p] = ld;
  }
}

// ---------------------------------------------------------------------------
// K2: sort-by-local-row (LDS int atomics = native ds_add_rtn_u32) then
// conflict-free register accumulation + shuffle reduce. R10: 64-entry main
// step with 4 entry/line chains; sched_barrier(0) between the load cluster
// and the FMA cluster pins all 4 ds_reads + 4 srcT loads to issue before
// any FMA waits (R9 showed the compiler otherwise reuses regs across the
// loads -- VGPR stayed 20, no real MLP). Two independent accumulators break
// the FMA dependency chain. Fallbacks: branch-free 32/16 steps + guarded
// tail. 512 threads, 8 waves, 33KB LDS -> 4 blocks/CU = 32 waves/CU.
// Epilogue: global unsafeAtomicAdd into z[8192][16], L2-resident.
__global__ __launch_bounds__(512, 8) void pass2_accum(
    const uint2* __restrict__ e1,
    const int* __restrict__ bcur,
    const float* __restrict__ srcT,     // [8320][16]
    float* __restrict__ z) {            // [N_RES][BATCH] (pre-zeroed)
  int bucket = blockIdx.y;
  int ch = blockIdx.x;
  int tid = threadIdx.x;

  int cnt = bcur[bucket];
  if (cnt > CAP1B) cnt = CAP1B;
  int base = ch * CHUNK2;
  if (base >= cnt) return;              // block-uniform early exit
  int n = cnt - base;
  if (n > CHUNK2) n = CHUNK2;

  __shared__ uint2 stg[CHUNK2];         // 32 KB
  __shared__ int hist[64];
  __shared__ int sbase[65];
  int wave = tid >> 6, lane = tid & 63;
  if (tid < 64) hist[tid] = 0;
  __syncthreads();

  const uint2* __restrict__ src = e1 + (size_t)bucket * CAP1B + base;
  uint2 ent[8];
  int lp[8];
  unsigned msk = 0;
#pragma unroll
  for (int g = 0; g < 4; ++g) {
    int i = (g * 512 + tid) * 2;        // paired entries, 16B aligned
    int e = g * 2;
    if (i + 1 < n) {
      uint4 q = *(const uint4*)(src + i);
      ent[e]     = make_uint2(q.x, q.y);
      ent[e + 1] = make_uint2(q.z, q.w);
      msk |= 3u << e;
      lp[e]     = atomicAdd(&hist[(ent[e].y >> 14) & 63u], 1);
      lp[e + 1] = atomicAdd(&hist[(ent[e + 1].y >> 14) & 63u], 1);
    } else if (i < n) {
      ent[e] = src[i];
      msk |= 1u << e;
      lp[e] = atomicAdd(&hist[(ent[e].y >> 14) & 63u], 1);
    }
  }
  __syncthreads();
  if (tid < 64) {                       // one wave: 64-bin exclusive scan
    int hh = hist[tid];
    int vv = hh;
#pragma unroll
    for (int d = 1; d < 64; d <<= 1) {
      int t = __shfl_up(vv, d);
      if (lane >= d) vv += t;
    }
    sbase[tid] = vv - hh;
    if (tid == 63) sbase[64] = vv;
  }
  __syncthreads();
#pragma unroll
  for (int e = 0; e < 8; ++e)
    if (msk & (1u << e))
      stg[sbase[(ent[e].y >> 14) & 63u] + lp[e]] = ent[e];
  __syncthreads();

  // Accumulation: wave handles rows wave*8..+7. 4-lane group (eoff=lane>>2)
  // broadcasts one stg entry and reads one 16B slice (bq=lane&3) of the 64B
  // srcT line; FMA into float4; shfl_xor{4,8,16,32} reduce; lanes 0..3 ->
  // 16 contiguous global fadds. Main loop wave-uniform, branch-free.
  int eoff = lane >> 2;
  int bq = lane & 3;
  const float4* __restrict__ s4 = (const float4*)srcT;

  for (int rr = wave * 8; rr < wave * 8 + 8; ++rr) {
    int s0 = sbase[rr], s1 = sbase[rr + 1];
    float4 accA = make_float4(0.f, 0.f, 0.f, 0.f);
    float4 accB = make_float4(0.f, 0.f, 0.f, 0.f);
    int i0 = s0;
    // 64-entry steps: 4 independent chains; loads pinned before FMAs.
    for (; i0 + 64 <= s1; i0 += 64) {
      uint2 eA = stg[i0 + eoff];
      uint2 eB = stg[i0 + 16 + eoff];
      uint2 eC = stg[i0 + 32 + eoff];
      uint2 eD = stg[i0 + 48 + eoff];
      float4 sA = s4[(int)(eA.y & 16383u) * 4 + bq];
      float4 sB = s4[(int)(eB.y & 16383u) * 4 + bq];
      float4 sC = s4[(int)(eC.y & 16383u) * 4 + bq];
      float4 sD = s4[(int)(eD.y & 16383u) * 4 + bq];
      __builtin_amdgcn_sched_barrier(0);   // issue all loads before FMAs
      float vA = __uint_as_float(eA.x);
      float vB = __uint_as_float(eB.x);
      float vC = __uint_as_float(eC.x);
      float vD = __uint_as_float(eD.x);
      accA.x += vA * sA.x; accA.y += vA * sA.y;
      accA.z += vA * sA.z; accA.w += vA * sA.w;
      accB.x += vB * sB.x; accB.y += vB * sB.y;
      accB.z += vB * sB.z; accB.w += vB * sB.w;
      accA.x += vC * sC.x; accA.y += vC * sC.y;
      accA.z += vC * sC.z; accA.w += vC * sC.w;
      accB.x += vD * sD.x; accB.y += vD * sD.y;
      accB.z += vD * sD.z; accB.w += vD * sD.w;
    }
    // 32-entry step (wave-uniform, branch-free body)
    if (i0 + 32 <= s1) {
      uint2 eA = stg[i0 + eoff];
      uint2 eB = stg[i0 + 16 + eoff];
      float4 sA = s4[(int)(eA.y & 16383u) * 4 + bq];
      float4 sB = s4[(int)(eB.y & 16383u) * 4 + bq];
      __builtin_amdgcn_sched_barrier(0);
      float vA = __uint_as_float(eA.x);
      float vB = __uint_as_float(eB.x);
      accA.x += vA * sA.x; accA.y += vA * sA.y;
      accA.z += vA * sA.z; accA.w += vA * sA.w;
      accB.x += vB * sB.x; accB.y += vB * sB.y;
      accB.z += vB * sB.z; accB.w += vB * sB.w;
      i0 += 32;
    }
    // 16-entry step
    if (i0 + 16 <= s1) {
      uint2 eA = stg[i0 + eoff];
      float4 sA = s4[(int)(eA.y & 16383u) * 4 + bq];
      float vA = __uint_as_float(eA.x);
      accA.x += vA * sA.x; accA.y += vA * sA.y;
      accA.z += vA * sA.z; accA.w += vA * sA.w;
      i0 += 16;
    }
    // guarded tail (<16 entries, divergent only here)
    if (i0 < s1) {
      int e = i0 + eoff;
      if (e < s1) {
        uint2 eA = stg[e];
        float4 sA = s4[(int)(eA.y & 16383u) * 4 + bq];
        float vA = __uint_as_float(eA.x);
        accA.x += vA * sA.x; accA.y += vA * sA.y;
        accA.z += vA * sA.z; accA.w += vA * sA.w;
      }
    }
    float4 acc = make_float4(accA.x + accB.x, accA.y + accB.y,
                             accA.z + accB.z, accA.w + accB.w);
#pragma unroll
    for (int m = 4; m <= 32; m <<= 1) {
      acc.x += __shfl_xor(acc.x, m);
      acc.y += __shfl_xor(acc.y, m);
      acc.z += __shfl_xor(acc.z, m);
      acc.w += __shfl_xor(acc.w, m);
    }
    if (lane < 4) {                     // lane == bq 0..3
      float* zp = z + (size_t)(bucket * 64 + rr) * BATCH + lane * 4;
      unsafeAtomicAdd(zp + 0, acc.x);
      unsafeAtomicAdd(zp + 1, acc.y);
      unsafeAtomicAdd(zp + 2, acc.z);
      unsafeAtomicAdd(zp + 3, acc.w);
    }
  }
}

// ---------------------------------------------------------------------------
__global__ __launch_bounds__(256) void finalize_z(
    const float* __restrict__ z, const float* __restrict__ state,
    const float* __restrict__ res_bias, const float* __restrict__ in_bias,
    float* __restrict__ out) {
  int tid = blockIdx.x * 256 + threadIdx.x;
  if (tid >= BATCH * N_RES) return;
  int b = tid >> 13;
  int r = tid & (N_RES - 1);
  float zz = z[r * 16 + b] + res_bias[r] + in_bias[r];
  out[tid] = (1.0f - LEAK) * state[tid] + LEAK * erff(zz);
}

// ---------------------------------------------------------------------------
// Fallback (small ws): atomic path, correct but slow.
__global__ __launch_bounds__(256) void transpose_nb(
    const float* __restrict__ state, const float* __restrict__ x,
    float* __restrict__ srcT) {
  int tid = blockIdx.x * 256 + threadIdx.x;
  if (tid < N_RES * BATCH) {
    int b = tid >> 13;
    int r = tid & (N_RES - 1);
    srcT[r * BATCH + b] = state[tid];
  }
  if (tid < N_IN * BATCH) {
    int b = tid >> 7;
    int c = tid & (N_IN - 1);
    srcT[(N_RES + c) * BATCH + b] = x[tid];
  }
}

__global__ __launch_bounds__(256) void spmm_atomic(
    const float* __restrict__ vals, const int* __restrict__ rows,
    const int* __restrict__ cols, const float* __restrict__ srcT,
    int col_off, float* __restrict__ zz, int nnz) {
  int i = blockIdx.x * blockDim.x + threadIdx.x;
  if (i >= nnz) return;
  float v = vals[i];
  int r = rows[i];
  int c = cols[i] + col_off;
  const float4* __restrict__ sp = (const float4*)(srcT + c * BATCH);
  float* zr = zz + r * BATCH;
#pragma unroll
  for (int qq = 0; qq < 4; ++qq) {
    float4 s = sp[qq];
    unsafeAtomicAdd(zr + qq * 4 + 0, v * s.x);
    unsafeAtomicAdd(zr + qq * 4 + 1, v * s.y);
    unsafeAtomicAdd(zr + qq * 4 + 2, v * s.z);
    unsafeAtomicAdd(zr + qq * 4 + 3, v * s.w);
  }
}

// ---------------------------------------------------------------------------
extern "C" void kernel_launch(void* const* d_in, const int* in_sizes, int n_in,
                              void* d_out, int out_size, void* d_ws, size_t ws_size,
                              hipStream_t stream) {
  const float* state    = (const float*)d_in[0];
  const float* x        = (const float*)d_in[1];
  const float* res_vals = (const float*)d_in[2];
  const int*   res_rows = (const int*)d_in[3];
  const int*   res_cols = (const int*)d_in[4];
  const float* res_bias = (const float*)d_in[5];
  const float* in_vals  = (const float*)d_in[6];
  const int*   in_rows  = (const int*)d_in[7];
  const int*   in_cols  = (const int*)d_in[8];
  const float* in_bias  = (const float*)d_in[9];

  const int res_nnz = in_sizes[2];
  const int in_nnz  = in_sizes[6];

  char* ws = (char*)d_ws;
  float* srcT = (float*)(ws + OFF_SRCT);
  float* z    = (float*)(ws + OFF_Z);
  float* out = (float*)d_out;

  if (ws_size >= REQ_A) {
    int* bcur = (int*)(ws + OFF_BCUR);
    uint2* e1 = (uint2*)(ws + OFF_E1);
    int nbres = (res_nnz + CHUNK1 - 1) / CHUNK1;
    int nbin  = (in_nnz + CHUNK1 - 1) / CHUNK1;
    int nchunks = nbres + nbin;

    hipMemsetAsync(bcur, 0, NBK * sizeof(int), stream);

    pass1_fused<<<nchunks + TBLK, 512, 0, stream>>>(
        state, x, res_vals, res_rows, res_cols, res_nnz, nbres,
        in_vals, in_rows, in_cols, in_nnz, nchunks, srcT, z, e1, bcur);

    pass2_accum<<<dim3(SB2, NBK), 512, 0, stream>>>(e1, bcur, srcT, z);

    finalize_z<<<512, 256, 0, stream>>>(z, state, res_bias, in_bias, out);
  } else {
    hipMemsetAsync(z, 0, N_RES * BATCH * sizeof(float), stream);
    transpose_nb<<<512, 256, 0, stream>>>(state, x, srcT);
    spmm_atomic<<<(res_nnz + 255) / 256, 256, 0, stream>>>(
        res_vals, res_rows, res_cols, srcT, 0, z, res_nnz);
    spmm_atomic<<<(in_nnz + 255) / 256, 256, 0, stream>>>(
        in_vals, in_rows, in_cols, srcT, N_RES, z, in_nnz);
    finalize_z<<<512, 256, 0, stream>>>(z, state, res_bias, in_bias, out);
  }
}

// Round 11
// 195.928 us; speedup vs baseline: 1.1222x; 1.0308x over previous
//
#include <hip/hip_runtime.h>
#include <math.h>

#define N_RES 8192
#define N_IN  128
#define BATCH 16
#define LEAK  0.9f

#define NBK    128     // buckets (row>>6), 64 rows each
#define CAP1B  55296   // per-bucket capacity (avg 53248, sigma~230, +8.9 sigma)
#define CHUNK1 8192    // pass1 entries per block (trend: 2048->77us, 4096->60us,
                       //  8192-><58us; per-block fixed costs dominate)
#define CHUNK2 8192    // pass2 entries per block (R11: 64KB stg @1024thr ->
                       //  2 blocks/CU x 16 waves = 32 waves/CU preserved,
                       //  half the blocks, double row segments)
#define SB2    7       // ceil(CAP1B / CHUNK2) chunks per bucket
#define TBLK   128     // transpose blocks appended to pass1 grid

// Entry encoding: y = (row << 14) | col, row 13 bits, col 14 bits (0..8319).
//   bucket = y >> 20 (row>>6); local row rr = (y >> 14) & 63; col = y & 16383.

// ws layout (bytes):
//   srcT @ 0      : [8320][16] f32 transposed state|x   (532,480)
//   bcur @ 1 MiB  : int[128]
//   z    @ 2 MiB  : [N_RES][BATCH] f32                  (524,288)
//   e1   @ 8 MiB  : uint2[NBK][CAP1B]                   (56,623,104)
// Falsified levers (do not retry):
//  R1/R2: FP atomicAdd/unsafeAtomicAdd on LDS -> CAS retry loop, 568us.
//  R5: line-padding bcur -> no change, +11MB HBM writes.
//  R6: fusing finalize into pass2 -> 430us latency pathology.
//  R8: predicated (clamp+mask) software pipeline -> +30% VALU, re-serialized.
//  R10: sched_barrier MLP raised VGPR 20->28 but time flat -> accumulate
//       latency already hidden; pass2 cost is fixed machinery, not MLP.
#define OFF_SRCT 0
#define OFF_BCUR (1u << 20)
#define OFF_Z    (2u << 20)
#define OFF_E1   (8u << 20)
#define REQ_A    ((size_t)OFF_E1 + (size_t)NBK * CAP1B * 8)   // ~62 MiB

// ---------------------------------------------------------------------------
// K1: pass1 binning (blocks [0, nchunks)) + transpose/z-zero (blocks
// [nchunks, +TBLK)). bcur must be zeroed before launch. srcT and z are
// consumed only by pass2/finalize (next dispatches) -> no intra-kernel
// ordering needed for the transpose section. 512 threads, CHUNK1=8192:
// 64KB stg -> 2 blocks/CU x 8 waves = 16 waves/CU. (R10: <58us.)
__global__ __launch_bounds__(512, 4) void pass1_fused(
    const float* __restrict__ state,   // [BATCH][N_RES]
    const float* __restrict__ x,       // [BATCH][N_IN]
    const float* __restrict__ vres, const int* __restrict__ rres,
    const int* __restrict__ cres, int nres, int nbres,
    const float* __restrict__ vin, const int* __restrict__ rin,
    const int* __restrict__ cin, int nin, int nchunks,
    float* __restrict__ srcT,          // [8320][16]
    float* __restrict__ z,             // [N_RES][BATCH] (zeroed here)
    uint2* __restrict__ e1,            // [NBK][CAP1B]
    int* __restrict__ bcur) {          // [NBK] (pre-zeroed)
  int tid = threadIdx.x;

  if (blockIdx.x >= nchunks) {         // ---- transpose + z-zero section ----
    int idx0 = (blockIdx.x - nchunks) * 512 + tid;
    const int stride = TBLK * 512;
    for (int i = idx0; i < N_RES * BATCH; i += stride) {
      int b = i >> 13;
      int r = i & (N_RES - 1);
      srcT[r * BATCH + b] = state[i];
      z[i] = 0.0f;
    }
    for (int i = idx0; i < N_IN * BATCH; i += stride) {
      int b = i >> 7;
      int c = i & (N_IN - 1);
      srcT[(N_RES + c) * BATCH + b] = x[i];
    }
    return;                            // block-uniform; no barriers used here
  }

  // ---- binning section ----
  const float* vals; const int* rows; const int* cols;
  int nnz, col_off, base;
  if (blockIdx.x < nbres) {
    vals = vres; rows = rres; cols = cres; nnz = nres; col_off = 0;
    base = blockIdx.x * CHUNK1;
  } else {
    vals = vin; rows = rin; cols = cin; nnz = nin; col_off = N_RES;
    base = (blockIdx.x - nbres) * CHUNK1;
  }

  __shared__ uint2 stg[CHUNK1];              // 64 KB
  __shared__ int hist[NBK];
  __shared__ int lbase[NBK];
  __shared__ int gbase[NBK];
  __shared__ int wsum[2];
  int wave = tid >> 6, lane = tid & 63;

  if (tid < NBK) hist[tid] = 0;
  __syncthreads();

  int n = nnz - base;
  if (n > CHUNK1) n = CHUNK1;

  uint2 ent[16];
  int lp[16];
  unsigned msk = 0;
#pragma unroll
  for (int g = 0; g < 4; ++g) {
    int i0 = (g * 512 + tid) * 4;            // 16B-aligned vector offset
    if (i0 + 3 < n) {
      int4 r4 = *(const int4*)(rows + base + i0);
      int4 c4 = *(const int4*)(cols + base + i0);
      float4 v4 = *(const float4*)(vals + base + i0);
      int rr_[4] = {r4.x, r4.y, r4.z, r4.w};
      int cc_[4] = {c4.x, c4.y, c4.z, c4.w};
      float vv_[4] = {v4.x, v4.y, v4.z, v4.w};
#pragma unroll
      for (int j = 0; j < 4; ++j) {
        int e = g * 4 + j;
        ent[e] = make_uint2(__float_as_uint(vv_[j]),
                            ((unsigned)rr_[j] << 14) |
                                (unsigned)(cc_[j] + col_off));
        msk |= 1u << e;
        lp[e] = atomicAdd(&hist[rr_[j] >> 6], 1);
      }
    } else {
#pragma unroll
      for (int j = 0; j < 4; ++j) {
        int e = g * 4 + j, i = i0 + j;
        if (i < n) {
          int r = rows[base + i];
          int c = cols[base + i] + col_off;
          float v = vals[base + i];
          ent[e] = make_uint2(__float_as_uint(v),
                              ((unsigned)r << 14) | (unsigned)c);
          msk |= 1u << e;
          lp[e] = atomicAdd(&hist[r >> 6], 1);
        }
      }
    }
  }
  __syncthreads();

  int h = 0, v = 0;
  if (tid < NBK) {                           // waves 0,1 scan 128 bins
    h = hist[tid];
    v = h;
#pragma unroll
    for (int d = 1; d < 64; d <<= 1) {
      int t = __shfl_up(v, d);
      if (lane >= d) v += t;
    }
    if (lane == 63) wsum[wave] = v;
  }
  __syncthreads();
  if (tid < NBK) {
    int off = (wave == 1) ? wsum[0] : 0;
    lbase[tid] = off + v - h;
    gbase[tid] = h ? atomicAdd(&bcur[tid], h) : 0;
  }
  __syncthreads();
#pragma unroll
  for (int e = 0; e < 16; ++e) {
    if (msk & (1u << e)) {
      int b = (int)(ent[e].y >> 20);         // recompute bin from packed row
      stg[lbase[b] + lp[e]] = ent[e];
    }
  }
  __syncthreads();
  for (int i = tid; i < n; i += 512) {
    uint2 ld = stg[i];
    int b = (int)(ld.y >> 20);
    int p = gbase[b] + (i - lbase[b]);
    if (p < CAP1B) e1[(size_t)b * CAP1B + p] = ld;
  }
}

// ---------------------------------------------------------------------------
// K2: sort-by-local-row (LDS int atomics = native ds_add_rtn_u32) then
// conflict-free register accumulation + shuffle reduce. R11 geometry:
// CHUNK2=8192 @1024 threads -> 64.6KB LDS, 2 blocks/CU x 16 waves =
// 32 waves/CU preserved; half the blocks (896), double row segments (~128
// entries) -> per-block fixed costs and per-row tails halve per entry.
// Accumulate body unchanged from R10 (64-step, 4 chains, sched_barrier).
// Epilogue: global unsafeAtomicAdd into z[8192][16], L2-resident.
__global__ __launch_bounds__(1024, 8) void pass2_accum(
    const uint2* __restrict__ e1,
    const int* __restrict__ bcur,
    const float* __restrict__ srcT,     // [8320][16]
    float* __restrict__ z) {            // [N_RES][BATCH] (pre-zeroed)
  int bucket = blockIdx.y;
  int ch = blockIdx.x;
  int tid = threadIdx.x;

  int cnt = bcur[bucket];
  if (cnt > CAP1B) cnt = CAP1B;
  int base = ch * CHUNK2;
  if (base >= cnt) return;              // block-uniform early exit
  int n = cnt - base;
  if (n > CHUNK2) n = CHUNK2;

  __shared__ uint2 stg[CHUNK2];         // 64 KB
  __shared__ int hist[64];
  __shared__ int sbase[65];
  int wave = tid >> 6, lane = tid & 63;
  if (tid < 64) hist[tid] = 0;
  __syncthreads();

  const uint2* __restrict__ src = e1 + (size_t)bucket * CAP1B + base;
  uint2 ent[8];
  int lp[8];
  unsigned msk = 0;
#pragma unroll
  for (int g = 0; g < 4; ++g) {
    int i = (g * 1024 + tid) * 2;       // paired entries, 16B aligned
    int e = g * 2;
    if (i + 1 < n) {
      uint4 q = *(const uint4*)(src + i);
      ent[e]     = make_uint2(q.x, q.y);
      ent[e + 1] = make_uint2(q.z, q.w);
      msk |= 3u << e;
      lp[e]     = atomicAdd(&hist[(ent[e].y >> 14) & 63u], 1);
      lp[e + 1] = atomicAdd(&hist[(ent[e + 1].y >> 14) & 63u], 1);
    } else if (i < n) {
      ent[e] = src[i];
      msk |= 1u << e;
      lp[e] = atomicAdd(&hist[(ent[e].y >> 14) & 63u], 1);
    }
  }
  __syncthreads();
  if (tid < 64) {                       // one wave: 64-bin exclusive scan
    int hh = hist[tid];
    int vv = hh;
#pragma unroll
    for (int d = 1; d < 64; d <<= 1) {
      int t = __shfl_up(vv, d);
      if (lane >= d) vv += t;
    }
    sbase[tid] = vv - hh;
    if (tid == 63) sbase[64] = vv;
  }
  __syncthreads();
#pragma unroll
  for (int e = 0; e < 8; ++e)
    if (msk & (1u << e))
      stg[sbase[(ent[e].y >> 14) & 63u] + lp[e]] = ent[e];
  __syncthreads();

  // Accumulation: wave handles rows wave*4..+3 (16 waves x 4 = 64 rows).
  // 4-lane group (eoff=lane>>2) broadcasts one stg entry and reads one 16B
  // slice (bq=lane&3) of the 64B srcT line; FMA into float4; shfl_xor
  // {4,8,16,32} reduce; lanes 0..3 -> 16 contiguous global fadds.
  int eoff = lane >> 2;
  int bq = lane & 3;
  const float4* __restrict__ s4 = (const float4*)srcT;

  for (int rr = wave * 4; rr < wave * 4 + 4; ++rr) {
    int s0 = sbase[rr], s1 = sbase[rr + 1];
    float4 accA = make_float4(0.f, 0.f, 0.f, 0.f);
    float4 accB = make_float4(0.f, 0.f, 0.f, 0.f);
    int i0 = s0;
    // 64-entry steps: 4 independent chains; loads pinned before FMAs.
    for (; i0 + 64 <= s1; i0 += 64) {
      uint2 eA = stg[i0 + eoff];
      uint2 eB = stg[i0 + 16 + eoff];
      uint2 eC = stg[i0 + 32 + eoff];
      uint2 eD = stg[i0 + 48 + eoff];
      float4 sA = s4[(int)(eA.y & 16383u) * 4 + bq];
      float4 sB = s4[(int)(eB.y & 16383u) * 4 + bq];
      float4 sC = s4[(int)(eC.y & 16383u) * 4 + bq];
      float4 sD = s4[(int)(eD.y & 16383u) * 4 + bq];
      __builtin_amdgcn_sched_barrier(0);   // issue all loads before FMAs
      float vA = __uint_as_float(eA.x);
      float vB = __uint_as_float(eB.x);
      float vC = __uint_as_float(eC.x);
      float vD = __uint_as_float(eD.x);
      accA.x += vA * sA.x; accA.y += vA * sA.y;
      accA.z += vA * sA.z; accA.w += vA * sA.w;
      accB.x += vB * sB.x; accB.y += vB * sB.y;
      accB.z += vB * sB.z; accB.w += vB * sB.w;
      accA.x += vC * sC.x; accA.y += vC * sC.y;
      accA.z += vC * sC.z; accA.w += vC * sC.w;
      accB.x += vD * sD.x; accB.y += vD * sD.y;
      accB.z += vD * sD.z; accB.w += vD * sD.w;
    }
    // 32-entry step (wave-uniform, branch-free body)
    if (i0 + 32 <= s1) {
      uint2 eA = stg[i0 + eoff];
      uint2 eB = stg[i0 + 16 + eoff];
      float4 sA = s4[(int)(eA.y & 16383u) * 4 + bq];
      float4 sB = s4[(int)(eB.y & 16383u) * 4 + bq];
      __builtin_amdgcn_sched_barrier(0);
      float vA = __uint_as_float(eA.x);
      float vB = __uint_as_float(eB.x);
      accA.x += vA * sA.x; accA.y += vA * sA.y;
      accA.z += vA * sA.z; accA.w += vA * sA.w;
      accB.x += vB * sB.x; accB.y += vB * sB.y;
      accB.z += vB * sB.z; accB.w += vB * sB.w;
      i0 += 32;
    }
    // 16-entry step
    if (i0 + 16 <= s1) {
      uint2 eA = stg[i0 + eoff];
      float4 sA = s4[(int)(eA.y & 16383u) * 4 + bq];
      float vA = __uint_as_float(eA.x);
      accA.x += vA * sA.x; accA.y += vA * sA.y;
      accA.z += vA * sA.z; accA.w += vA * sA.w;
      i0 += 16;
    }
    // guarded tail (<16 entries, divergent only here)
    if (i0 < s1) {
      int e = i0 + eoff;
      if (e < s1) {
        uint2 eA = stg[e];
        float4 sA = s4[(int)(eA.y & 16383u) * 4 + bq];
        float vA = __uint_as_float(eA.x);
        accA.x += vA * sA.x; accA.y += vA * sA.y;
        accA.z += vA * sA.z; accA.w += vA * sA.w;
      }
    }
    float4 acc = make_float4(accA.x + accB.x, accA.y + accB.y,
                             accA.z + accB.z, accA.w + accB.w);
#pragma unroll
    for (int m = 4; m <= 32; m <<= 1) {
      acc.x += __shfl_xor(acc.x, m);
      acc.y += __shfl_xor(acc.y, m);
      acc.z += __shfl_xor(acc.z, m);
      acc.w += __shfl_xor(acc.w, m);
    }
    if (lane < 4) {                     // lane == bq 0..3
      float* zp = z + (size_t)(bucket * 64 + rr) * BATCH + lane * 4;
      unsafeAtomicAdd(zp + 0, acc.x);
      unsafeAtomicAdd(zp + 1, acc.y);
      unsafeAtomicAdd(zp + 2, acc.z);
      unsafeAtomicAdd(zp + 3, acc.w);
    }
  }
}

// ---------------------------------------------------------------------------
__global__ __launch_bounds__(256) void finalize_z(
    const float* __restrict__ z, const float* __restrict__ state,
    const float* __restrict__ res_bias, const float* __restrict__ in_bias,
    float* __restrict__ out) {
  int tid = blockIdx.x * 256 + threadIdx.x;
  if (tid >= BATCH * N_RES) return;
  int b = tid >> 13;
  int r = tid & (N_RES - 1);
  float zz = z[r * 16 + b] + res_bias[r] + in_bias[r];
  out[tid] = (1.0f - LEAK) * state[tid] + LEAK * erff(zz);
}

// ---------------------------------------------------------------------------
// Fallback (small ws): atomic path, correct but slow.
__global__ __launch_bounds__(256) void transpose_nb(
    const float* __restrict__ state, const float* __restrict__ x,
    float* __restrict__ srcT) {
  int tid = blockIdx.x * 256 + threadIdx.x;
  if (tid < N_RES * BATCH) {
    int b = tid >> 13;
    int r = tid & (N_RES - 1);
    srcT[r * BATCH + b] = state[tid];
  }
  if (tid < N_IN * BATCH) {
    int b = tid >> 7;
    int c = tid & (N_IN - 1);
    srcT[(N_RES + c) * BATCH + b] = x[tid];
  }
}

__global__ __launch_bounds__(256) void spmm_atomic(
    const float* __restrict__ vals, const int* __restrict__ rows,
    const int* __restrict__ cols, const float* __restrict__ srcT,
    int col_off, float* __restrict__ zz, int nnz) {
  int i = blockIdx.x * blockDim.x + threadIdx.x;
  if (i >= nnz) return;
  float v = vals[i];
  int r = rows[i];
  int c = cols[i] + col_off;
  const float4* __restrict__ sp = (const float4*)(srcT + c * BATCH);
  float* zr = zz + r * BATCH;
#pragma unroll
  for (int qq = 0; qq < 4; ++qq) {
    float4 s = sp[qq];
    unsafeAtomicAdd(zr + qq * 4 + 0, v * s.x);
    unsafeAtomicAdd(zr + qq * 4 + 1, v * s.y);
    unsafeAtomicAdd(zr + qq * 4 + 2, v * s.z);
    unsafeAtomicAdd(zr + qq * 4 + 3, v * s.w);
  }
}

// ---------------------------------------------------------------------------
extern "C" void kernel_launch(void* const* d_in, const int* in_sizes, int n_in,
                              void* d_out, int out_size, void* d_ws, size_t ws_size,
                              hipStream_t stream) {
  const float* state    = (const float*)d_in[0];
  const float* x        = (const float*)d_in[1];
  const float* res_vals = (const float*)d_in[2];
  const int*   res_rows = (const int*)d_in[3];
  const int*   res_cols = (const int*)d_in[4];
  const float* res_bias = (const float*)d_in[5];
  const float* in_vals  = (const float*)d_in[6];
  const int*   in_rows  = (const int*)d_in[7];
  const int*   in_cols  = (const int*)d_in[8];
  const float* in_bias  = (const float*)d_in[9];

  const int res_nnz = in_sizes[2];
  const int in_nnz  = in_sizes[6];

  char* ws = (char*)d_ws;
  float* srcT = (float*)(ws + OFF_SRCT);
  float* z    = (float*)(ws + OFF_Z);
  float* out = (float*)d_out;

  if (ws_size >= REQ_A) {
    int* bcur = (int*)(ws + OFF_BCUR);
    uint2* e1 = (uint2*)(ws + OFF_E1);
    int nbres = (res_nnz + CHUNK1 - 1) / CHUNK1;
    int nbin  = (in_nnz + CHUNK1 - 1) / CHUNK1;
    int nchunks = nbres + nbin;

    hipMemsetAsync(bcur, 0, NBK * sizeof(int), stream);

    pass1_fused<<<nchunks + TBLK, 512, 0, stream>>>(
        state, x, res_vals, res_rows, res_cols, res_nnz, nbres,
        in_vals, in_rows, in_cols, in_nnz, nchunks, srcT, z, e1, bcur);

    pass2_accum<<<dim3(SB2, NBK), 1024, 0, stream>>>(e1, bcur, srcT, z);

    finalize_z<<<512, 256, 0, stream>>>(z, state, res_bias, in_bias, out);
  } else {
    hipMemsetAsync(z, 0, N_RES * BATCH * sizeof(float), stream);
    transpose_nb<<<512, 256, 0, stream>>>(state, x, srcT);
    spmm_atomic<<<(res_nnz + 255) / 256, 256, 0, stream>>>(
        res_vals, res_rows, res_cols, srcT, 0, z, res_nnz);
    spmm_atomic<<<(in_nnz + 255) / 256, 256, 0, stream>>>(
        in_vals, in_rows, in_cols, srcT, N_RES, z, in_nnz);
    finalize_z<<<512, 256, 0, stream>>>(z, state, res_bias, in_bias, out);
  }
}

// Round 12
// 193.651 us; speedup vs baseline: 1.1354x; 1.0118x over previous
//
#include <hip/hip_runtime.h>
#include <math.h>

#define N_RES 8192
#define N_IN  128
#define BATCH 16
#define LEAK  0.9f

#define NBK    128     // buckets (row>>6), 64 rows each
#define CAP1B  55296   // per-bucket capacity (avg 53248, sigma~230, +8.9 sigma)
#define CHUNK1 8192    // pass1 entries per block (trend: 2048->77us, 4096->60us,
                       //  8192-><58us; per-block fixed costs dominate)
#define CHUNK2 8192    // pass2 entries per block (R11: 64KB stg @1024thr ->
                       //  2 blocks/CU x 16 waves = 32 waves/CU, 54us)
#define SB2    7       // ceil(CAP1B / CHUNK2) chunks per bucket
#define TBLK   128     // transpose blocks appended to pass1 grid

// Entry encoding: y = (row << 14) | col, row 13 bits, col 14 bits (0..8319).
//   bucket = y >> 20 (row>>6); local row rr = (y >> 14) & 63; col = y & 16383.

// ws layout (bytes):
//   srcT @ 0      : [8320][16] f32 transposed state|x   (532,480)
//   bcur @ 1 MiB  : int[128]
//   z    @ 2 MiB  : [N_RES][BATCH] f32                  (524,288)
//   e1   @ 8 MiB  : uint2[NBK][CAP1B]                   (56,623,104)
// Falsified levers (do not retry):
//  R1/R2: FP atomicAdd/unsafeAtomicAdd on LDS -> CAS retry loop, 568us.
//  R5: line-padding bcur -> no change, +11MB HBM writes.
//  R6: fusing finalize into pass2 -> 430us latency pathology.
//  R8: predicated (clamp+mask) software pipeline -> +30% VALU, re-serialized.
//  R10: sched_barrier MLP raised VGPR 20->28 but time flat -> accumulate
//       latency already hidden; pass2 cost is fixed machinery, not MLP.
// Proven levers: bigger chunks (fewer blocks), more threads at fixed chunk
//  (R3->R4: 256->512thr = -22%; R12 applies the same to pass1: 512->1024).
#define OFF_SRCT 0
#define OFF_BCUR (1u << 20)
#define OFF_Z    (2u << 20)
#define OFF_E1   (8u << 20)
#define REQ_A    ((size_t)OFF_E1 + (size_t)NBK * CAP1B * 8)   // ~62 MiB

// ---------------------------------------------------------------------------
// K1: pass1 binning (blocks [0, nchunks)) + transpose/z-zero (blocks
// [nchunks, +TBLK)). bcur must be zeroed before launch. srcT and z are
// consumed only by pass2/finalize (next dispatches) -> no intra-kernel
// ordering needed for the transpose section. R12: 1024 threads @ CHUNK1=8192
// (64KB stg): 2 blocks/CU x 16 waves = 32 waves/CU (was 16 at 512thr) --
// same per-block fixed costs, double the latency-hiding TLP.
__global__ __launch_bounds__(1024, 8) void pass1_fused(
    const float* __restrict__ state,   // [BATCH][N_RES]
    const float* __restrict__ x,       // [BATCH][N_IN]
    const float* __restrict__ vres, const int* __restrict__ rres,
    const int* __restrict__ cres, int nres, int nbres,
    const float* __restrict__ vin, const int* __restrict__ rin,
    const int* __restrict__ cin, int nin, int nchunks,
    float* __restrict__ srcT,          // [8320][16]
    float* __restrict__ z,             // [N_RES][BATCH] (zeroed here)
    uint2* __restrict__ e1,            // [NBK][CAP1B]
    int* __restrict__ bcur) {          // [NBK] (pre-zeroed)
  int tid = threadIdx.x;

  if (blockIdx.x >= nchunks) {         // ---- transpose + z-zero section ----
    int idx0 = (blockIdx.x - nchunks) * 1024 + tid;
    const int stride = TBLK * 1024;
    for (int i = idx0; i < N_RES * BATCH; i += stride) {
      int b = i >> 13;
      int r = i & (N_RES - 1);
      srcT[r * BATCH + b] = state[i];
      z[i] = 0.0f;
    }
    for (int i = idx0; i < N_IN * BATCH; i += stride) {
      int b = i >> 7;
      int c = i & (N_IN - 1);
      srcT[(N_RES + c) * BATCH + b] = x[i];
    }
    return;                            // block-uniform; no barriers used here
  }

  // ---- binning section ----
  const float* vals; const int* rows; const int* cols;
  int nnz, col_off, base;
  if (blockIdx.x < nbres) {
    vals = vres; rows = rres; cols = cres; nnz = nres; col_off = 0;
    base = blockIdx.x * CHUNK1;
  } else {
    vals = vin; rows = rin; cols = cin; nnz = nin; col_off = N_RES;
    base = (blockIdx.x - nbres) * CHUNK1;
  }

  __shared__ uint2 stg[CHUNK1];              // 64 KB
  __shared__ int hist[NBK];
  __shared__ int lbase[NBK];
  __shared__ int gbase[NBK];
  __shared__ int wsum[2];
  int wave = tid >> 6, lane = tid & 63;

  if (tid < NBK) hist[tid] = 0;
  __syncthreads();

  int n = nnz - base;
  if (n > CHUNK1) n = CHUNK1;

  uint2 ent[8];
  int lp[8];
  unsigned msk = 0;
#pragma unroll
  for (int g = 0; g < 2; ++g) {
    int i0 = (g * 1024 + tid) * 4;           // 16B-aligned vector offset
    if (i0 + 3 < n) {
      int4 r4 = *(const int4*)(rows + base + i0);
      int4 c4 = *(const int4*)(cols + base + i0);
      float4 v4 = *(const float4*)(vals + base + i0);
      int rr_[4] = {r4.x, r4.y, r4.z, r4.w};
      int cc_[4] = {c4.x, c4.y, c4.z, c4.w};
      float vv_[4] = {v4.x, v4.y, v4.z, v4.w};
#pragma unroll
      for (int j = 0; j < 4; ++j) {
        int e = g * 4 + j;
        ent[e] = make_uint2(__float_as_uint(vv_[j]),
                            ((unsigned)rr_[j] << 14) |
                                (unsigned)(cc_[j] + col_off));
        msk |= 1u << e;
        lp[e] = atomicAdd(&hist[rr_[j] >> 6], 1);
      }
    } else {
#pragma unroll
      for (int j = 0; j < 4; ++j) {
        int e = g * 4 + j, i = i0 + j;
        if (i < n) {
          int r = rows[base + i];
          int c = cols[base + i] + col_off;
          float v = vals[base + i];
          ent[e] = make_uint2(__float_as_uint(v),
                              ((unsigned)r << 14) | (unsigned)c);
          msk |= 1u << e;
          lp[e] = atomicAdd(&hist[r >> 6], 1);
        }
      }
    }
  }
  __syncthreads();

  int h = 0, v = 0;
  if (tid < NBK) {                           // waves 0,1 scan 128 bins
    h = hist[tid];
    v = h;
#pragma unroll
    for (int d = 1; d < 64; d <<= 1) {
      int t = __shfl_up(v, d);
      if (lane >= d) v += t;
    }
    if (lane == 63) wsum[wave] = v;
  }
  __syncthreads();
  if (tid < NBK) {
    int off = (wave == 1) ? wsum[0] : 0;
    lbase[tid] = off + v - h;
    gbase[tid] = h ? atomicAdd(&bcur[tid], h) : 0;
  }
  __syncthreads();
#pragma unroll
  for (int e = 0; e < 8; ++e) {
    if (msk & (1u << e)) {
      int b = (int)(ent[e].y >> 20);         // recompute bin from packed row
      stg[lbase[b] + lp[e]] = ent[e];
    }
  }
  __syncthreads();
  for (int i = tid; i < n; i += 1024) {
    uint2 ld = stg[i];
    int b = (int)(ld.y >> 20);
    int p = gbase[b] + (i - lbase[b]);
    if (p < CAP1B) e1[(size_t)b * CAP1B + p] = ld;
  }
}

// ---------------------------------------------------------------------------
// K2: EXACT R11 version (54us). Sort-by-local-row (LDS int atomics = native
// ds_add_rtn_u32) then conflict-free register accumulation + shuffle reduce.
// CHUNK2=8192 @1024 threads -> 64.6KB LDS, 2 blocks/CU x 16 waves =
// 32 waves/CU. Epilogue: global unsafeAtomicAdd into z[8192][16].
__global__ __launch_bounds__(1024, 8) void pass2_accum(
    const uint2* __restrict__ e1,
    const int* __restrict__ bcur,
    const float* __restrict__ srcT,     // [8320][16]
    float* __restrict__ z) {            // [N_RES][BATCH] (pre-zeroed)
  int bucket = blockIdx.y;
  int ch = blockIdx.x;
  int tid = threadIdx.x;

  int cnt = bcur[bucket];
  if (cnt > CAP1B) cnt = CAP1B;
  int base = ch * CHUNK2;
  if (base >= cnt) return;              // block-uniform early exit
  int n = cnt - base;
  if (n > CHUNK2) n = CHUNK2;

  __shared__ uint2 stg[CHUNK2];         // 64 KB
  __shared__ int hist[64];
  __shared__ int sbase[65];
  int wave = tid >> 6, lane = tid & 63;
  if (tid < 64) hist[tid] = 0;
  __syncthreads();

  const uint2* __restrict__ src = e1 + (size_t)bucket * CAP1B + base;
  uint2 ent[8];
  int lp[8];
  unsigned msk = 0;
#pragma unroll
  for (int g = 0; g < 4; ++g) {
    int i = (g * 1024 + tid) * 2;       // paired entries, 16B aligned
    int e = g * 2;
    if (i + 1 < n) {
      uint4 q = *(const uint4*)(src + i);
      ent[e]     = make_uint2(q.x, q.y);
      ent[e + 1] = make_uint2(q.z, q.w);
      msk |= 3u << e;
      lp[e]     = atomicAdd(&hist[(ent[e].y >> 14) & 63u], 1);
      lp[e + 1] = atomicAdd(&hist[(ent[e + 1].y >> 14) & 63u], 1);
    } else if (i < n) {
      ent[e] = src[i];
      msk |= 1u << e;
      lp[e] = atomicAdd(&hist[(ent[e].y >> 14) & 63u], 1);
    }
  }
  __syncthreads();
  if (tid < 64) {                       // one wave: 64-bin exclusive scan
    int hh = hist[tid];
    int vv = hh;
#pragma unroll
    for (int d = 1; d < 64; d <<= 1) {
      int t = __shfl_up(vv, d);
      if (lane >= d) vv += t;
    }
    sbase[tid] = vv - hh;
    if (tid == 63) sbase[64] = vv;
  }
  __syncthreads();
#pragma unroll
  for (int e = 0; e < 8; ++e)
    if (msk & (1u << e))
      stg[sbase[(ent[e].y >> 14) & 63u] + lp[e]] = ent[e];
  __syncthreads();

  // Accumulation: wave handles rows wave*4..+3 (16 waves x 4 = 64 rows).
  // 4-lane group (eoff=lane>>2) broadcasts one stg entry and reads one 16B
  // slice (bq=lane&3) of the 64B srcT line; FMA into float4; shfl_xor
  // {4,8,16,32} reduce; lanes 0..3 -> 16 contiguous global fadds.
  int eoff = lane >> 2;
  int bq = lane & 3;
  const float4* __restrict__ s4 = (const float4*)srcT;

  for (int rr = wave * 4; rr < wave * 4 + 4; ++rr) {
    int s0 = sbase[rr], s1 = sbase[rr + 1];
    float4 accA = make_float4(0.f, 0.f, 0.f, 0.f);
    float4 accB = make_float4(0.f, 0.f, 0.f, 0.f);
    int i0 = s0;
    // 64-entry steps: 4 independent chains; loads pinned before FMAs.
    for (; i0 + 64 <= s1; i0 += 64) {
      uint2 eA = stg[i0 + eoff];
      uint2 eB = stg[i0 + 16 + eoff];
      uint2 eC = stg[i0 + 32 + eoff];
      uint2 eD = stg[i0 + 48 + eoff];
      float4 sA = s4[(int)(eA.y & 16383u) * 4 + bq];
      float4 sB = s4[(int)(eB.y & 16383u) * 4 + bq];
      float4 sC = s4[(int)(eC.y & 16383u) * 4 + bq];
      float4 sD = s4[(int)(eD.y & 16383u) * 4 + bq];
      __builtin_amdgcn_sched_barrier(0);   // issue all loads before FMAs
      float vA = __uint_as_float(eA.x);
      float vB = __uint_as_float(eB.x);
      float vC = __uint_as_float(eC.x);
      float vD = __uint_as_float(eD.x);
      accA.x += vA * sA.x; accA.y += vA * sA.y;
      accA.z += vA * sA.z; accA.w += vA * sA.w;
      accB.x += vB * sB.x; accB.y += vB * sB.y;
      accB.z += vB * sB.z; accB.w += vB * sB.w;
      accA.x += vC * sC.x; accA.y += vC * sC.y;
      accA.z += vC * sC.z; accA.w += vC * sC.w;
      accB.x += vD * sD.x; accB.y += vD * sD.y;
      accB.z += vD * sD.z; accB.w += vD * sD.w;
    }
    // 32-entry step (wave-uniform, branch-free body)
    if (i0 + 32 <= s1) {
      uint2 eA = stg[i0 + eoff];
      uint2 eB = stg[i0 + 16 + eoff];
      float4 sA = s4[(int)(eA.y & 16383u) * 4 + bq];
      float4 sB = s4[(int)(eB.y & 16383u) * 4 + bq];
      __builtin_amdgcn_sched_barrier(0);
      float vA = __uint_as_float(eA.x);
      float vB = __uint_as_float(eB.x);
      accA.x += vA * sA.x; accA.y += vA * sA.y;
      accA.z += vA * sA.z; accA.w += vA * sA.w;
      accB.x += vB * sB.x; accB.y += vB * sB.y;
      accB.z += vB * sB.z; accB.w += vB * sB.w;
      i0 += 32;
    }
    // 16-entry step
    if (i0 + 16 <= s1) {
      uint2 eA = stg[i0 + eoff];
      float4 sA = s4[(int)(eA.y & 16383u) * 4 + bq];
      float vA = __uint_as_float(eA.x);
      accA.x += vA * sA.x; accA.y += vA * sA.y;
      accA.z += vA * sA.z; accA.w += vA * sA.w;
      i0 += 16;
    }
    // guarded tail (<16 entries, divergent only here)
    if (i0 < s1) {
      int e = i0 + eoff;
      if (e < s1) {
        uint2 eA = stg[e];
        float4 sA = s4[(int)(eA.y & 16383u) * 4 + bq];
        float vA = __uint_as_float(eA.x);
        accA.x += vA * sA.x; accA.y += vA * sA.y;
        accA.z += vA * sA.z; accA.w += vA * sA.w;
      }
    }
    float4 acc = make_float4(accA.x + accB.x, accA.y + accB.y,
                             accA.z + accB.z, accA.w + accB.w);
#pragma unroll
    for (int m = 4; m <= 32; m <<= 1) {
      acc.x += __shfl_xor(acc.x, m);
      acc.y += __shfl_xor(acc.y, m);
      acc.z += __shfl_xor(acc.z, m);
      acc.w += __shfl_xor(acc.w, m);
    }
    if (lane < 4) {                     // lane == bq 0..3
      float* zp = z + (size_t)(bucket * 64 + rr) * BATCH + lane * 4;
      unsafeAtomicAdd(zp + 0, acc.x);
      unsafeAtomicAdd(zp + 1, acc.y);
      unsafeAtomicAdd(zp + 2, acc.z);
      unsafeAtomicAdd(zp + 3, acc.w);
    }
  }
}

// ---------------------------------------------------------------------------
__global__ __launch_bounds__(256) void finalize_z(
    const float* __restrict__ z, const float* __restrict__ state,
    const float* __restrict__ res_bias, const float* __restrict__ in_bias,
    float* __restrict__ out) {
  int tid = blockIdx.x * 256 + threadIdx.x;
  if (tid >= BATCH * N_RES) return;
  int b = tid >> 13;
  int r = tid & (N_RES - 1);
  float zz = z[r * 16 + b] + res_bias[r] + in_bias[r];
  out[tid] = (1.0f - LEAK) * state[tid] + LEAK * erff(zz);
}

// ---------------------------------------------------------------------------
// Fallback (small ws): atomic path, correct but slow.
__global__ __launch_bounds__(256) void transpose_nb(
    const float* __restrict__ state, const float* __restrict__ x,
    float* __restrict__ srcT) {
  int tid = blockIdx.x * 256 + threadIdx.x;
  if (tid < N_RES * BATCH) {
    int b = tid >> 13;
    int r = tid & (N_RES - 1);
    srcT[r * BATCH + b] = state[tid];
  }
  if (tid < N_IN * BATCH) {
    int b = tid >> 7;
    int c = tid & (N_IN - 1);
    srcT[(N_RES + c) * BATCH + b] = x[tid];
  }
}

__global__ __launch_bounds__(256) void spmm_atomic(
    const float* __restrict__ vals, const int* __restrict__ rows,
    const int* __restrict__ cols, const float* __restrict__ srcT,
    int col_off, float* __restrict__ zz, int nnz) {
  int i = blockIdx.x * blockDim.x + threadIdx.x;
  if (i >= nnz) return;
  float v = vals[i];
  int r = rows[i];
  int c = cols[i] + col_off;
  const float4* __restrict__ sp = (const float4*)(srcT + c * BATCH);
  float* zr = zz + r * BATCH;
#pragma unroll
  for (int qq = 0; qq < 4; ++qq) {
    float4 s = sp[qq];
    unsafeAtomicAdd(zr + qq * 4 + 0, v * s.x);
    unsafeAtomicAdd(zr + qq * 4 + 1, v * s.y);
    unsafeAtomicAdd(zr + qq * 4 + 2, v * s.z);
    unsafeAtomicAdd(zr + qq * 4 + 3, v * s.w);
  }
}

// ---------------------------------------------------------------------------
extern "C" void kernel_launch(void* const* d_in, const int* in_sizes, int n_in,
                              void* d_out, int out_size, void* d_ws, size_t ws_size,
                              hipStream_t stream) {
  const float* state    = (const float*)d_in[0];
  const float* x        = (const float*)d_in[1];
  const float* res_vals = (const float*)d_in[2];
  const int*   res_rows = (const int*)d_in[3];
  const int*   res_cols = (const int*)d_in[4];
  const float* res_bias = (const float*)d_in[5];
  const float* in_vals  = (const float*)d_in[6];
  const int*   in_rows  = (const int*)d_in[7];
  const int*   in_cols  = (const int*)d_in[8];
  const float* in_bias  = (const float*)d_in[9];

  const int res_nnz = in_sizes[2];
  const int in_nnz  = in_sizes[6];

  char* ws = (char*)d_ws;
  float* srcT = (float*)(ws + OFF_SRCT);
  float* z    = (float*)(ws + OFF_Z);
  float* out = (float*)d_out;

  if (ws_size >= REQ_A) {
    int* bcur = (int*)(ws + OFF_BCUR);
    uint2* e1 = (uint2*)(ws + OFF_E1);
    int nbres = (res_nnz + CHUNK1 - 1) / CHUNK1;
    int nbin  = (in_nnz + CHUNK1 - 1) / CHUNK1;
    int nchunks = nbres + nbin;

    hipMemsetAsync(bcur, 0, NBK * sizeof(int), stream);

    pass1_fused<<<nchunks + TBLK, 1024, 0, stream>>>(
        state, x, res_vals, res_rows, res_cols, res_nnz, nbres,
        in_vals, in_rows, in_cols, in_nnz, nchunks, srcT, z, e1, bcur);

    pass2_accum<<<dim3(SB2, NBK), 1024, 0, stream>>>(e1, bcur, srcT, z);

    finalize_z<<<512, 256, 0, stream>>>(z, state, res_bias, in_bias, out);
  } else {
    hipMemsetAsync(z, 0, N_RES * BATCH * sizeof(float), stream);
    transpose_nb<<<512, 256, 0, stream>>>(state, x, srcT);
    spmm_atomic<<<(res_nnz + 255) / 256, 256, 0, stream>>>(
        res_vals, res_rows, res_cols, srcT, 0, z, res_nnz);
    spmm_atomic<<<(in_nnz + 255) / 256, 256, 0, stream>>>(
        in_vals, in_rows, in_cols, srcT, N_RES, z, in_nnz);
    finalize_z<<<512, 256, 0, stream>>>(z, state, res_bias, in_bias, out);
  }
}

// Round 13
// 191.689 us; speedup vs baseline: 1.1471x; 1.0102x over previous
//
#include <hip/hip_runtime.h>
#include <math.h>

#define N_RES 8192
#define N_IN  128
#define BATCH 16
#define LEAK  0.9f

#define NBK    128     // buckets (row>>6), 64 rows each
#define CAP1B  55296   // per-bucket capacity (avg 53248, sigma~230, +8.9 sigma)
#define CHUNK1 8192    // pass1 entries per block (2048->77us, 4096->60us, 8192 best)
#define CHUNK2 8192    // pass2 entries per block
#define SB2    7       // ceil(CAP1B / CHUNK2) chunks per bucket
#define TBLK   128     // transpose blocks appended to pass1 grid

// Entry encoding: y = (row << 14) | col, row 13 bits, col 14 bits (0..8319).
//   bucket = y >> 20 (row>>6); local row rr = (y >> 14) & 63; col = y & 16383.

// ws layout (bytes):
//   srcT @ 0      : [8320][16] f32 transposed state|x   (532,480)
//   bcur @ 1 MiB  : int[128]
//   z    @ 2 MiB  : [N_RES][BATCH] f32                  (524,288)
//   e1   @ 8 MiB  : uint2[NBK][CAP1B]                   (56,623,104)
// Falsified levers (do not retry):
//  R1/R2: FP atomicAdd/unsafeAtomicAdd on LDS -> CAS retry loop, 568us.
//         (INT LDS atomics are native ds_add - that is R13's basis.)
//  R5: line-padding bcur -> no change, +11MB HBM writes.
//  R6: fusing finalize into pass2 -> 430us latency pathology.
//  R8: predicated software pipeline -> +30% VALU, compiler re-serialized.
//  R10: sched_barrier MLP -> VGPR 20->28, time flat (latency already hidden).
#define OFF_SRCT 0
#define OFF_BCUR (1u << 20)
#define OFF_Z    (2u << 20)
#define OFF_E1   (8u << 20)
#define REQ_A    ((size_t)OFF_E1 + (size_t)NBK * CAP1B * 8)   // ~62 MiB

// ---------------------------------------------------------------------------
// K1: EXACT R12 version (<52us). pass1 binning (blocks [0, nchunks)) +
// transpose/z-zero (blocks [nchunks, +TBLK)). bcur pre-zeroed. 1024 threads
// @ CHUNK1=8192 (64KB stg): 2 blocks/CU x 16 waves = 32 waves/CU.
__global__ __launch_bounds__(1024, 8) void pass1_fused(
    const float* __restrict__ state,   // [BATCH][N_RES]
    const float* __restrict__ x,       // [BATCH][N_IN]
    const float* __restrict__ vres, const int* __restrict__ rres,
    const int* __restrict__ cres, int nres, int nbres,
    const float* __restrict__ vin, const int* __restrict__ rin,
    const int* __restrict__ cin, int nin, int nchunks,
    float* __restrict__ srcT,          // [8320][16]
    float* __restrict__ z,             // [N_RES][BATCH] (zeroed here)
    uint2* __restrict__ e1,            // [NBK][CAP1B]
    int* __restrict__ bcur) {          // [NBK] (pre-zeroed)
  int tid = threadIdx.x;

  if (blockIdx.x >= nchunks) {         // ---- transpose + z-zero section ----
    int idx0 = (blockIdx.x - nchunks) * 1024 + tid;
    const int stride = TBLK * 1024;
    for (int i = idx0; i < N_RES * BATCH; i += stride) {
      int b = i >> 13;
      int r = i & (N_RES - 1);
      srcT[r * BATCH + b] = state[i];
      z[i] = 0.0f;
    }
    for (int i = idx0; i < N_IN * BATCH; i += stride) {
      int b = i >> 7;
      int c = i & (N_IN - 1);
      srcT[(N_RES + c) * BATCH + b] = x[i];
    }
    return;                            // block-uniform; no barriers used here
  }

  // ---- binning section ----
  const float* vals; const int* rows; const int* cols;
  int nnz, col_off, base;
  if (blockIdx.x < nbres) {
    vals = vres; rows = rres; cols = cres; nnz = nres; col_off = 0;
    base = blockIdx.x * CHUNK1;
  } else {
    vals = vin; rows = rin; cols = cin; nnz = nin; col_off = N_RES;
    base = (blockIdx.x - nbres) * CHUNK1;
  }

  __shared__ uint2 stg[CHUNK1];              // 64 KB
  __shared__ int hist[NBK];
  __shared__ int lbase[NBK];
  __shared__ int gbase[NBK];
  __shared__ int wsum[2];
  int wave = tid >> 6, lane = tid & 63;

  if (tid < NBK) hist[tid] = 0;
  __syncthreads();

  int n = nnz - base;
  if (n > CHUNK1) n = CHUNK1;

  uint2 ent[8];
  int lp[8];
  unsigned msk = 0;
#pragma unroll
  for (int g = 0; g < 2; ++g) {
    int i0 = (g * 1024 + tid) * 4;           // 16B-aligned vector offset
    if (i0 + 3 < n) {
      int4 r4 = *(const int4*)(rows + base + i0);
      int4 c4 = *(const int4*)(cols + base + i0);
      float4 v4 = *(const float4*)(vals + base + i0);
      int rr_[4] = {r4.x, r4.y, r4.z, r4.w};
      int cc_[4] = {c4.x, c4.y, c4.z, c4.w};
      float vv_[4] = {v4.x, v4.y, v4.z, v4.w};
#pragma unroll
      for (int j = 0; j < 4; ++j) {
        int e = g * 4 + j;
        ent[e] = make_uint2(__float_as_uint(vv_[j]),
                            ((unsigned)rr_[j] << 14) |
                                (unsigned)(cc_[j] + col_off));
        msk |= 1u << e;
        lp[e] = atomicAdd(&hist[rr_[j] >> 6], 1);
      }
    } else {
#pragma unroll
      for (int j = 0; j < 4; ++j) {
        int e = g * 4 + j, i = i0 + j;
        if (i < n) {
          int r = rows[base + i];
          int c = cols[base + i] + col_off;
          float v = vals[base + i];
          ent[e] = make_uint2(__float_as_uint(v),
                              ((unsigned)r << 14) | (unsigned)c);
          msk |= 1u << e;
          lp[e] = atomicAdd(&hist[r >> 6], 1);
        }
      }
    }
  }
  __syncthreads();

  int h = 0, v = 0;
  if (tid < NBK) {                           // waves 0,1 scan 128 bins
    h = hist[tid];
    v = h;
#pragma unroll
    for (int d = 1; d < 64; d <<= 1) {
      int t = __shfl_up(v, d);
      if (lane >= d) v += t;
    }
    if (lane == 63) wsum[wave] = v;
  }
  __syncthreads();
  if (tid < NBK) {
    int off = (wave == 1) ? wsum[0] : 0;
    lbase[tid] = off + v - h;
    gbase[tid] = h ? atomicAdd(&bcur[tid], h) : 0;
  }
  __syncthreads();
#pragma unroll
  for (int e = 0; e < 8; ++e) {
    if (msk & (1u << e)) {
      int b = (int)(ent[e].y >> 20);         // recompute bin from packed row
      stg[lbase[b] + lp[e]] = ent[e];
    }
  }
  __syncthreads();
  for (int i = tid; i < n; i += 1024) {
    uint2 ld = stg[i];
    int b = (int)(ld.y >> 20);
    int p = gbase[b] + (i - lbase[b]);
    if (p < CAP1B) e1[(size_t)b * CAP1B + p] = ld;
  }
}

// ---------------------------------------------------------------------------
// K2 (R13): SORT-FREE fixed-point accumulation. The R12 sort structure was
// latency-bound with 2 blocks/CU (64KB stg caps residency during its
// barrier-chained phases). Here: acc[64][17] INT accumulator (2^-16 scale,
// 4.4KB LDS) + native ds_add (int LDS atomics are HW-fast; only FP LDS
// atomics are the R1/R2 CAS trap). Per 4-lane group: broadcast e1 entry,
// one 16B slice of the 64B srcT line, 4 mul + 4 rn-cvt + 4 fire-and-forget
// ds_add. No hist/scan/scatter/stg, no hot-loop barriers; 4 blocks/CU x 8
// waves = 32 waves/CU with true phase overlap. Pad 17: bank = (17*rr+b)%32
// bijective in rr -> conflicts only on genuine same-row collisions.
// Numerics: |term| < ~2M, |row sum| < ~1e7 << 2^31; rounding noise
// ~0.5*sqrt(819)*2^-16 ~= 2.2e-4 << 7.8e-3 tol. Readback: 1024 global
// unsafeAtomicAdd into z. Grid: (SB2, NBK), 512 threads.
__global__ __launch_bounds__(512, 8) void pass2_accum(
    const uint2* __restrict__ e1,
    const int* __restrict__ bcur,
    const float* __restrict__ srcT,     // [8320][16]
    float* __restrict__ z) {            // [N_RES][BATCH] (pre-zeroed)
  int bucket = blockIdx.y;
  int ch = blockIdx.x;
  int tid = threadIdx.x;

  int cnt = bcur[bucket];
  if (cnt > CAP1B) cnt = CAP1B;
  int base = ch * CHUNK2;
  if (base >= cnt) return;              // block-uniform early exit
  int n = cnt - base;
  if (n > CHUNK2) n = CHUNK2;

  __shared__ int acc[64 * 17];          // 4352 B, fixed-point 2^-16
  for (int i = tid; i < 64 * 17; i += 512) acc[i] = 0;
  __syncthreads();

  const uint2* __restrict__ src = e1 + (size_t)bucket * CAP1B + base;
  int wave = tid >> 6, lane = tid & 63;
  int g = lane >> 2;                    // entry slot within 16-entry step
  int bq = lane & 3;                    // batch quad
  const float4* __restrict__ s4 = (const float4*)srcT;

  // Each wave owns a contiguous 1024-entry span; 2 entries per group per
  // iteration (2 independent chains), clamp+mask for the ragged end.
  int bw = wave * (CHUNK2 / 8);
  int lim = n - bw;
  if (lim > CHUNK2 / 8) lim = CHUNK2 / 8;
  for (int s = 0; s < lim; s += 32) {
    int i1 = bw + s + g;
    int i2 = bw + s + 16 + g;
    int c1 = (i1 < n) ? i1 : n - 1;
    int c2 = (i2 < n) ? i2 : n - 1;
    uint2 eA = src[c1];
    uint2 eB = src[c2];
    float4 sA = s4[(int)(eA.y & 16383u) * 4 + bq];
    float4 sB = s4[(int)(eB.y & 16383u) * 4 + bq];
    float vA = (i1 < n) ? __uint_as_float(eA.x) * 65536.f : 0.0f;
    float vB = (i2 < n) ? __uint_as_float(eB.x) * 65536.f : 0.0f;
    int aA = (int)((eA.y >> 14) & 63u) * 17 + (bq << 2);
    int aB = (int)((eB.y >> 14) & 63u) * 17 + (bq << 2);
    atomicAdd(&acc[aA + 0], __float2int_rn(vA * sA.x));
    atomicAdd(&acc[aA + 1], __float2int_rn(vA * sA.y));
    atomicAdd(&acc[aA + 2], __float2int_rn(vA * sA.z));
    atomicAdd(&acc[aA + 3], __float2int_rn(vA * sA.w));
    atomicAdd(&acc[aB + 0], __float2int_rn(vB * sB.x));
    atomicAdd(&acc[aB + 1], __float2int_rn(vB * sB.y));
    atomicAdd(&acc[aB + 2], __float2int_rn(vB * sB.z));
    atomicAdd(&acc[aB + 3], __float2int_rn(vB * sB.w));
  }
  __syncthreads();
  // Readback: convert and add into z (multiple chunks per bucket -> atomic).
  for (int i = tid; i < 64 * BATCH; i += 512) {
    int rr = i >> 4, b = i & 15;
    float fv = (float)acc[rr * 17 + b] * (1.0f / 65536.f);
    unsafeAtomicAdd(&z[(size_t)(bucket * 64 + rr) * BATCH + b], fv);
  }
}

// ---------------------------------------------------------------------------
__global__ __launch_bounds__(256) void finalize_z(
    const float* __restrict__ z, const float* __restrict__ state,
    const float* __restrict__ res_bias, const float* __restrict__ in_bias,
    float* __restrict__ out) {
  int tid = blockIdx.x * 256 + threadIdx.x;
  if (tid >= BATCH * N_RES) return;
  int b = tid >> 13;
  int r = tid & (N_RES - 1);
  float zz = z[r * 16 + b] + res_bias[r] + in_bias[r];
  out[tid] = (1.0f - LEAK) * state[tid] + LEAK * erff(zz);
}

// ---------------------------------------------------------------------------
// Fallback (small ws): atomic path, correct but slow.
__global__ __launch_bounds__(256) void transpose_nb(
    const float* __restrict__ state, const float* __restrict__ x,
    float* __restrict__ srcT) {
  int tid = blockIdx.x * 256 + threadIdx.x;
  if (tid < N_RES * BATCH) {
    int b = tid >> 13;
    int r = tid & (N_RES - 1);
    srcT[r * BATCH + b] = state[tid];
  }
  if (tid < N_IN * BATCH) {
    int b = tid >> 7;
    int c = tid & (N_IN - 1);
    srcT[(N_RES + c) * BATCH + b] = x[tid];
  }
}

__global__ __launch_bounds__(256) void spmm_atomic(
    const float* __restrict__ vals, const int* __restrict__ rows,
    const int* __restrict__ cols, const float* __restrict__ srcT,
    int col_off, float* __restrict__ zz, int nnz) {
  int i = blockIdx.x * blockDim.x + threadIdx.x;
  if (i >= nnz) return;
  float v = vals[i];
  int r = rows[i];
  int c = cols[i] + col_off;
  const float4* __restrict__ sp = (const float4*)(srcT + c * BATCH);
  float* zr = zz + r * BATCH;
#pragma unroll
  for (int qq = 0; qq < 4; ++qq) {
    float4 s = sp[qq];
    unsafeAtomicAdd(zr + qq * 4 + 0, v * s.x);
    unsafeAtomicAdd(zr + qq * 4 + 1, v * s.y);
    unsafeAtomicAdd(zr + qq * 4 + 2, v * s.z);
    unsafeAtomicAdd(zr + qq * 4 + 3, v * s.w);
  }
}

// ---------------------------------------------------------------------------
extern "C" void kernel_launch(void* const* d_in, const int* in_sizes, int n_in,
                              void* d_out, int out_size, void* d_ws, size_t ws_size,
                              hipStream_t stream) {
  const float* state    = (const float*)d_in[0];
  const float* x        = (const float*)d_in[1];
  const float* res_vals = (const float*)d_in[2];
  const int*   res_rows = (const int*)d_in[3];
  const int*   res_cols = (const int*)d_in[4];
  const float* res_bias = (const float*)d_in[5];
  const float* in_vals  = (const float*)d_in[6];
  const int*   in_rows  = (const int*)d_in[7];
  const int*   in_cols  = (const int*)d_in[8];
  const float* in_bias  = (const float*)d_in[9];

  const int res_nnz = in_sizes[2];
  const int in_nnz  = in_sizes[6];

  char* ws = (char*)d_ws;
  float* srcT = (float*)(ws + OFF_SRCT);
  float* z    = (float*)(ws + OFF_Z);
  float* out = (float*)d_out;

  if (ws_size >= REQ_A) {
    int* bcur = (int*)(ws + OFF_BCUR);
    uint2* e1 = (uint2*)(ws + OFF_E1);
    int nbres = (res_nnz + CHUNK1 - 1) / CHUNK1;
    int nbin  = (in_nnz + CHUNK1 - 1) / CHUNK1;
    int nchunks = nbres + nbin;

    hipMemsetAsync(bcur, 0, NBK * sizeof(int), stream);

    pass1_fused<<<nchunks + TBLK, 1024, 0, stream>>>(
        state, x, res_vals, res_rows, res_cols, res_nnz, nbres,
        in_vals, in_rows, in_cols, in_nnz, nchunks, srcT, z, e1, bcur);

    pass2_accum<<<dim3(SB2, NBK), 512, 0, stream>>>(e1, bcur, srcT, z);

    finalize_z<<<512, 256, 0, stream>>>(z, state, res_bias, in_bias, out);
  } else {
    hipMemsetAsync(z, 0, N_RES * BATCH * sizeof(float), stream);
    transpose_nb<<<512, 256, 0, stream>>>(state, x, srcT);
    spmm_atomic<<<(res_nnz + 255) / 256, 256, 0, stream>>>(
        res_vals, res_rows, res_cols, srcT, 0, z, res_nnz);
    spmm_atomic<<<(in_nnz + 255) / 256, 256, 0, stream>>>(
        in_vals, in_rows, in_cols, srcT, N_RES, z, in_nnz);
    finalize_z<<<512, 256, 0, stream>>>(z, state, res_bias, in_bias, out);
  }
}

// Round 14
// 185.879 us; speedup vs baseline: 1.1829x; 1.0313x over previous
//
#include <hip/hip_runtime.h>
#include <math.h>

#define N_RES 8192
#define N_IN  128
#define BATCH 16
#define LEAK  0.9f

#define NBK    128     // buckets (row>>6), 64 rows each
#define CAP1B  55296   // per-bucket capacity (avg 53248, sigma~230, +8.9 sigma)
#define CHUNK1 8192    // pass1 entries per block (2048->77us, 4096->60us, 8192 best)
#define CHUNK2 4096    // pass2 entries per block (R14: R13's 8192 gave only
                       //  896 blocks = 3.5/CU vs 4-block wave-slot capacity ->
                       //  grid-limited 51% occupancy; 4096 -> 1792 blocks fills)
#define SB2    14      // ceil(CAP1B / CHUNK2) chunks per bucket
#define TBLK   128     // transpose blocks appended to pass1 grid

// Entry encoding: y = (row << 14) | col, row 13 bits, col 14 bits (0..8319).
//   bucket = y >> 20 (row>>6); local row rr = (y >> 14) & 63; col = y & 16383.

// ws layout (bytes):
//   srcT @ 0      : [8320][16] f32 transposed state|x   (532,480)
//   bcur @ 1 MiB  : int[128]
//   z    @ 2 MiB  : [N_RES][BATCH] f32                  (524,288)
//   e1   @ 8 MiB  : uint2[NBK][CAP1B]                   (56,623,104)
// Falsified levers (do not retry):
//  R1/R2: FP atomicAdd/unsafeAtomicAdd on LDS -> CAS retry loop, 568us.
//         (INT LDS atomics are native ds_add - R13+ basis.)
//  R5: line-padding bcur -> no change, +11MB HBM writes.
//  R6: fusing finalize into pass2 -> 430us latency pathology.
//  R8: predicated software pipeline -> +30% VALU, compiler re-serialized.
//  R10: sched_barrier MLP -> VGPR 20->28, time flat.
//  R13 lesson: sort-free int-atomic accum works (51us) but was GRID-limited
//       at CHUNK2=8192 (896 blocks, 51% occupancy).
#define OFF_SRCT 0
#define OFF_BCUR (1u << 20)
#define OFF_Z    (2u << 20)
#define OFF_E1   (8u << 20)
#define REQ_A    ((size_t)OFF_E1 + (size_t)NBK * CAP1B * 8)   // ~62 MiB

// ---------------------------------------------------------------------------
// K1: EXACT R12 version (<52us). pass1 binning (blocks [0, nchunks)) +
// transpose/z-zero (blocks [nchunks, +TBLK)). bcur pre-zeroed. 1024 threads
// @ CHUNK1=8192 (64KB stg): 2 blocks/CU x 16 waves = 32 waves/CU.
__global__ __launch_bounds__(1024, 8) void pass1_fused(
    const float* __restrict__ state,   // [BATCH][N_RES]
    const float* __restrict__ x,       // [BATCH][N_IN]
    const float* __restrict__ vres, const int* __restrict__ rres,
    const int* __restrict__ cres, int nres, int nbres,
    const float* __restrict__ vin, const int* __restrict__ rin,
    const int* __restrict__ cin, int nin, int nchunks,
    float* __restrict__ srcT,          // [8320][16]
    float* __restrict__ z,             // [N_RES][BATCH] (zeroed here)
    uint2* __restrict__ e1,            // [NBK][CAP1B]
    int* __restrict__ bcur) {          // [NBK] (pre-zeroed)
  int tid = threadIdx.x;

  if (blockIdx.x >= nchunks) {         // ---- transpose + z-zero section ----
    int idx0 = (blockIdx.x - nchunks) * 1024 + tid;
    const int stride = TBLK * 1024;
    for (int i = idx0; i < N_RES * BATCH; i += stride) {
      int b = i >> 13;
      int r = i & (N_RES - 1);
      srcT[r * BATCH + b] = state[i];
      z[i] = 0.0f;
    }
    for (int i = idx0; i < N_IN * BATCH; i += stride) {
      int b = i >> 7;
      int c = i & (N_IN - 1);
      srcT[(N_RES + c) * BATCH + b] = x[i];
    }
    return;                            // block-uniform; no barriers used here
  }

  // ---- binning section ----
  const float* vals; const int* rows; const int* cols;
  int nnz, col_off, base;
  if (blockIdx.x < nbres) {
    vals = vres; rows = rres; cols = cres; nnz = nres; col_off = 0;
    base = blockIdx.x * CHUNK1;
  } else {
    vals = vin; rows = rin; cols = cin; nnz = nin; col_off = N_RES;
    base = (blockIdx.x - nbres) * CHUNK1;
  }

  __shared__ uint2 stg[CHUNK1];              // 64 KB
  __shared__ int hist[NBK];
  __shared__ int lbase[NBK];
  __shared__ int gbase[NBK];
  __shared__ int wsum[2];
  int wave = tid >> 6, lane = tid & 63;

  if (tid < NBK) hist[tid] = 0;
  __syncthreads();

  int n = nnz - base;
  if (n > CHUNK1) n = CHUNK1;

  uint2 ent[8];
  int lp[8];
  unsigned msk = 0;
#pragma unroll
  for (int g = 0; g < 2; ++g) {
    int i0 = (g * 1024 + tid) * 4;           // 16B-aligned vector offset
    if (i0 + 3 < n) {
      int4 r4 = *(const int4*)(rows + base + i0);
      int4 c4 = *(const int4*)(cols + base + i0);
      float4 v4 = *(const float4*)(vals + base + i0);
      int rr_[4] = {r4.x, r4.y, r4.z, r4.w};
      int cc_[4] = {c4.x, c4.y, c4.z, c4.w};
      float vv_[4] = {v4.x, v4.y, v4.z, v4.w};
#pragma unroll
      for (int j = 0; j < 4; ++j) {
        int e = g * 4 + j;
        ent[e] = make_uint2(__float_as_uint(vv_[j]),
                            ((unsigned)rr_[j] << 14) |
                                (unsigned)(cc_[j] + col_off));
        msk |= 1u << e;
        lp[e] = atomicAdd(&hist[rr_[j] >> 6], 1);
      }
    } else {
#pragma unroll
      for (int j = 0; j < 4; ++j) {
        int e = g * 4 + j, i = i0 + j;
        if (i < n) {
          int r = rows[base + i];
          int c = cols[base + i] + col_off;
          float v = vals[base + i];
          ent[e] = make_uint2(__float_as_uint(v),
                              ((unsigned)r << 14) | (unsigned)c);
          msk |= 1u << e;
          lp[e] = atomicAdd(&hist[r >> 6], 1);
        }
      }
    }
  }
  __syncthreads();

  int h = 0, v = 0;
  if (tid < NBK) {                           // waves 0,1 scan 128 bins
    h = hist[tid];
    v = h;
#pragma unroll
    for (int d = 1; d < 64; d <<= 1) {
      int t = __shfl_up(v, d);
      if (lane >= d) v += t;
    }
    if (lane == 63) wsum[wave] = v;
  }
  __syncthreads();
  if (tid < NBK) {
    int off = (wave == 1) ? wsum[0] : 0;
    lbase[tid] = off + v - h;
    gbase[tid] = h ? atomicAdd(&bcur[tid], h) : 0;
  }
  __syncthreads();
#pragma unroll
  for (int e = 0; e < 8; ++e) {
    if (msk & (1u << e)) {
      int b = (int)(ent[e].y >> 20);         // recompute bin from packed row
      stg[lbase[b] + lp[e]] = ent[e];
    }
  }
  __syncthreads();
  for (int i = tid; i < n; i += 1024) {
    uint2 ld = stg[i];
    int b = (int)(ld.y >> 20);
    int p = gbase[b] + (i - lbase[b]);
    if (p < CAP1B) e1[(size_t)b * CAP1B + p] = ld;
  }
}

// ---------------------------------------------------------------------------
// K2 (R13 structure, R14 grid): sort-free fixed-point accumulation.
// acc[64][17] INT accumulator (2^-16 scale, 4.4KB LDS) + native ds_add.
// Per 4-lane group: broadcast e1 entry, one 16B slice of the 64B srcT line,
// 4 mul + 4 rn-cvt + 4 fire-and-forget ds_add. No hist/scan/scatter/stg,
// no hot-loop barriers. CHUNK2=4096 -> 1792 blocks -> 4 blocks/CU x 8 waves
// = full 32 waves/CU (R13's 8192 was grid-limited at 51% occupancy).
// Pad 17: bank = (17*rr+b)%32 bijective in rr. Numerics: |row sum| < ~1e7
// << 2^31; rounding noise ~2.2e-4 << 7.8e-3 tol. Readback: 1024 global
// unsafeAtomicAdd into z. Grid: (SB2, NBK), 512 threads.
__global__ __launch_bounds__(512, 8) void pass2_accum(
    const uint2* __restrict__ e1,
    const int* __restrict__ bcur,
    const float* __restrict__ srcT,     // [8320][16]
    float* __restrict__ z) {            // [N_RES][BATCH] (pre-zeroed)
  int bucket = blockIdx.y;
  int ch = blockIdx.x;
  int tid = threadIdx.x;

  int cnt = bcur[bucket];
  if (cnt > CAP1B) cnt = CAP1B;
  int base = ch * CHUNK2;
  if (base >= cnt) return;              // block-uniform early exit
  int n = cnt - base;
  if (n > CHUNK2) n = CHUNK2;

  __shared__ int acc[64 * 17];          // 4352 B, fixed-point 2^-16
  for (int i = tid; i < 64 * 17; i += 512) acc[i] = 0;
  __syncthreads();

  const uint2* __restrict__ src = e1 + (size_t)bucket * CAP1B + base;
  int wave = tid >> 6, lane = tid & 63;
  int g = lane >> 2;                    // entry slot within 16-entry step
  int bq = lane & 3;                    // batch quad
  const float4* __restrict__ s4 = (const float4*)srcT;

  // Each wave owns a contiguous span; 2 entries per group per iteration
  // (2 independent chains), clamp+mask for the ragged end.
  int bw = wave * (CHUNK2 / 8);
  int lim = n - bw;
  if (lim > CHUNK2 / 8) lim = CHUNK2 / 8;
  for (int s = 0; s < lim; s += 32) {
    int i1 = bw + s + g;
    int i2 = bw + s + 16 + g;
    int c1 = (i1 < n) ? i1 : n - 1;
    int c2 = (i2 < n) ? i2 : n - 1;
    uint2 eA = src[c1];
    uint2 eB = src[c2];
    float4 sA = s4[(int)(eA.y & 16383u) * 4 + bq];
    float4 sB = s4[(int)(eB.y & 16383u) * 4 + bq];
    float vA = (i1 < n) ? __uint_as_float(eA.x) * 65536.f : 0.0f;
    float vB = (i2 < n) ? __uint_as_float(eB.x) * 65536.f : 0.0f;
    int aA = (int)((eA.y >> 14) & 63u) * 17 + (bq << 2);
    int aB = (int)((eB.y >> 14) & 63u) * 17 + (bq << 2);
    atomicAdd(&acc[aA + 0], __float2int_rn(vA * sA.x));
    atomicAdd(&acc[aA + 1], __float2int_rn(vA * sA.y));
    atomicAdd(&acc[aA + 2], __float2int_rn(vA * sA.z));
    atomicAdd(&acc[aA + 3], __float2int_rn(vA * sA.w));
    atomicAdd(&acc[aB + 0], __float2int_rn(vB * sB.x));
    atomicAdd(&acc[aB + 1], __float2int_rn(vB * sB.y));
    atomicAdd(&acc[aB + 2], __float2int_rn(vB * sB.z));
    atomicAdd(&acc[aB + 3], __float2int_rn(vB * sB.w));
  }
  __syncthreads();
  // Readback: convert and add into z (multiple chunks per bucket -> atomic).
  for (int i = tid; i < 64 * BATCH; i += 512) {
    int rr = i >> 4, b = i & 15;
    float fv = (float)acc[rr * 17 + b] * (1.0f / 65536.f);
    unsafeAtomicAdd(&z[(size_t)(bucket * 64 + rr) * BATCH + b], fv);
  }
}

// ---------------------------------------------------------------------------
__global__ __launch_bounds__(256) void finalize_z(
    const float* __restrict__ z, const float* __restrict__ state,
    const float* __restrict__ res_bias, const float* __restrict__ in_bias,
    float* __restrict__ out) {
  int tid = blockIdx.x * 256 + threadIdx.x;
  if (tid >= BATCH * N_RES) return;
  int b = tid >> 13;
  int r = tid & (N_RES - 1);
  float zz = z[r * 16 + b] + res_bias[r] + in_bias[r];
  out[tid] = (1.0f - LEAK) * state[tid] + LEAK * erff(zz);
}

// ---------------------------------------------------------------------------
// Fallback (small ws): atomic path, correct but slow.
__global__ __launch_bounds__(256) void transpose_nb(
    const float* __restrict__ state, const float* __restrict__ x,
    float* __restrict__ srcT) {
  int tid = blockIdx.x * 256 + threadIdx.x;
  if (tid < N_RES * BATCH) {
    int b = tid >> 13;
    int r = tid & (N_RES - 1);
    srcT[r * BATCH + b] = state[tid];
  }
  if (tid < N_IN * BATCH) {
    int b = tid >> 7;
    int c = tid & (N_IN - 1);
    srcT[(N_RES + c) * BATCH + b] = x[tid];
  }
}

__global__ __launch_bounds__(256) void spmm_atomic(
    const float* __restrict__ vals, const int* __restrict__ rows,
    const int* __restrict__ cols, const float* __restrict__ srcT,
    int col_off, float* __restrict__ zz, int nnz) {
  int i = blockIdx.x * blockDim.x + threadIdx.x;
  if (i >= nnz) return;
  float v = vals[i];
  int r = rows[i];
  int c = cols[i] + col_off;
  const float4* __restrict__ sp = (const float4*)(srcT + c * BATCH);
  float* zr = zz + r * BATCH;
#pragma unroll
  for (int qq = 0; qq < 4; ++qq) {
    float4 s = sp[qq];
    unsafeAtomicAdd(zr + qq * 4 + 0, v * s.x);
    unsafeAtomicAdd(zr + qq * 4 + 1, v * s.y);
    unsafeAtomicAdd(zr + qq * 4 + 2, v * s.z);
    unsafeAtomicAdd(zr + qq * 4 + 3, v * s.w);
  }
}

// ---------------------------------------------------------------------------
extern "C" void kernel_launch(void* const* d_in, const int* in_sizes, int n_in,
                              void* d_out, int out_size, void* d_ws, size_t ws_size,
                              hipStream_t stream) {
  const float* state    = (const float*)d_in[0];
  const float* x        = (const float*)d_in[1];
  const float* res_vals = (const float*)d_in[2];
  const int*   res_rows = (const int*)d_in[3];
  const int*   res_cols = (const int*)d_in[4];
  const float* res_bias = (const float*)d_in[5];
  const float* in_vals  = (const float*)d_in[6];
  const int*   in_rows  = (const int*)d_in[7];
  const int*   in_cols  = (const int*)d_in[8];
  const float* in_bias  = (const float*)d_in[9];

  const int res_nnz = in_sizes[2];
  const int in_nnz  = in_sizes[6];

  char* ws = (char*)d_ws;
  float* srcT = (float*)(ws + OFF_SRCT);
  float* z    = (float*)(ws + OFF_Z);
  float* out = (float*)d_out;

  if (ws_size >= REQ_A) {
    int* bcur = (int*)(ws + OFF_BCUR);
    uint2* e1 = (uint2*)(ws + OFF_E1);
    int nbres = (res_nnz + CHUNK1 - 1) / CHUNK1;
    int nbin  = (in_nnz + CHUNK1 - 1) / CHUNK1;
    int nchunks = nbres + nbin;

    hipMemsetAsync(bcur, 0, NBK * sizeof(int), stream);

    pass1_fused<<<nchunks + TBLK, 1024, 0, stream>>>(
        state, x, res_vals, res_rows, res_cols, res_nnz, nbres,
        in_vals, in_rows, in_cols, in_nnz, nchunks, srcT, z, e1, bcur);

    pass2_accum<<<dim3(SB2, NBK), 512, 0, stream>>>(e1, bcur, srcT, z);

    finalize_z<<<512, 256, 0, stream>>>(z, state, res_bias, in_bias, out);
  } else {
    hipMemsetAsync(z, 0, N_RES * BATCH * sizeof(float), stream);
    transpose_nb<<<512, 256, 0, stream>>>(state, x, srcT);
    spmm_atomic<<<(res_nnz + 255) / 256, 256, 0, stream>>>(
        res_vals, res_rows, res_cols, srcT, 0, z, res_nnz);
    spmm_atomic<<<(in_nnz + 255) / 256, 256, 0, stream>>>(
        in_vals, in_rows, in_cols, srcT, N_RES, z, in_nnz);
    finalize_z<<<512, 256, 0, stream>>>(z, state, res_bias, in_bias, out);
  }
}

// Round 15
// 184.009 us; speedup vs baseline: 1.1949x; 1.0102x over previous
//
#include <hip/hip_runtime.h>
#include <math.h>

#define N_RES 8192
#define N_IN  128
#define BATCH 16
#define LEAK  0.9f

#define NBK    128     // buckets (row>>6), 64 rows each
#define CAP1B  55296   // per-bucket capacity (avg 53248, sigma~230, +8.9 sigma)
#define CHUNK1 8192    // pass1 entries per block (2048->77us, 4096->60us, 8192 best)
#define CHUNK2 4096    // pass2 entries per block (1792 blocks fills 4-block/CU
                       //  wave-slot capacity; R13's 8192 was grid-limited)
#define SB2    14      // ceil(CAP1B / CHUNK2) chunks per bucket
#define TBLK   128     // transpose blocks appended to pass1 grid
#define CPAD   1089    // per-copy acc stride (64*17 + 1: +1 rotates banks/copy)

// Entry encoding: y = (row << 14) | col, row 13 bits, col 14 bits (0..8319).
//   bucket = y >> 20 (row>>6); local row rr = (y >> 14) & 63; col = y & 16383.

// ws layout (bytes):
//   srcT @ 0      : [8320][16] f32 transposed state|x   (532,480)
//   bcur @ 1 MiB  : int[128]
//   z    @ 2 MiB  : [N_RES][BATCH] f32                  (524,288)
//   e1   @ 8 MiB  : uint2[NBK][CAP1B]                   (56,623,104)
// Falsified levers (do not retry):
//  R1/R2: FP atomicAdd/unsafeAtomicAdd on LDS -> CAS retry loop, 568us.
//         (INT LDS atomics are native ds_add - R13+ basis.)
//  R5: line-padding bcur -> no change, +11MB HBM writes.
//  R6: fusing finalize into pass2 -> 430us latency pathology.
//  R8: predicated software pipeline -> +30% VALU, compiler re-serialized.
//  R10: sched_barrier MLP -> VGPR 20->28, time flat.
//  R13: CHUNK2=8192 grid-limited (896 blocks, 51% occ); 4096 fixed it (R14).
// R15: pass2 same-address ds_add collisions = 6.9M conflict-cycles (25% of
//  pass2 runtime, R14 PMC) -> 4-way replicated accumulator, copy = slot&3.
#define OFF_SRCT 0
#define OFF_BCUR (1u << 20)
#define OFF_Z    (2u << 20)
#define OFF_E1   (8u << 20)
#define REQ_A    ((size_t)OFF_E1 + (size_t)NBK * CAP1B * 8)   // ~62 MiB

// ---------------------------------------------------------------------------
// K1: EXACT R12 version (45.9us @ R14). pass1 binning (blocks [0, nchunks))
// + transpose/z-zero (blocks [nchunks, +TBLK)). bcur pre-zeroed. 1024
// threads @ CHUNK1=8192 (64KB stg): 2 blocks/CU x 16 waves = 32 waves/CU.
__global__ __launch_bounds__(1024, 8) void pass1_fused(
    const float* __restrict__ state,   // [BATCH][N_RES]
    const float* __restrict__ x,       // [BATCH][N_IN]
    const float* __restrict__ vres, const int* __restrict__ rres,
    const int* __restrict__ cres, int nres, int nbres,
    const float* __restrict__ vin, const int* __restrict__ rin,
    const int* __restrict__ cin, int nin, int nchunks,
    float* __restrict__ srcT,          // [8320][16]
    float* __restrict__ z,             // [N_RES][BATCH] (zeroed here)
    uint2* __restrict__ e1,            // [NBK][CAP1B]
    int* __restrict__ bcur) {          // [NBK] (pre-zeroed)
  int tid = threadIdx.x;

  if (blockIdx.x >= nchunks) {         // ---- transpose + z-zero section ----
    int idx0 = (blockIdx.x - nchunks) * 1024 + tid;
    const int stride = TBLK * 1024;
    for (int i = idx0; i < N_RES * BATCH; i += stride) {
      int b = i >> 13;
      int r = i & (N_RES - 1);
      srcT[r * BATCH + b] = state[i];
      z[i] = 0.0f;
    }
    for (int i = idx0; i < N_IN * BATCH; i += stride) {
      int b = i >> 7;
      int c = i & (N_IN - 1);
      srcT[(N_RES + c) * BATCH + b] = x[i];
    }
    return;                            // block-uniform; no barriers used here
  }

  // ---- binning section ----
  const float* vals; const int* rows; const int* cols;
  int nnz, col_off, base;
  if (blockIdx.x < nbres) {
    vals = vres; rows = rres; cols = cres; nnz = nres; col_off = 0;
    base = blockIdx.x * CHUNK1;
  } else {
    vals = vin; rows = rin; cols = cin; nnz = nin; col_off = N_RES;
    base = (blockIdx.x - nbres) * CHUNK1;
  }

  __shared__ uint2 stg[CHUNK1];              // 64 KB
  __shared__ int hist[NBK];
  __shared__ int lbase[NBK];
  __shared__ int gbase[NBK];
  __shared__ int wsum[2];
  int wave = tid >> 6, lane = tid & 63;

  if (tid < NBK) hist[tid] = 0;
  __syncthreads();

  int n = nnz - base;
  if (n > CHUNK1) n = CHUNK1;

  uint2 ent[8];
  int lp[8];
  unsigned msk = 0;
#pragma unroll
  for (int g = 0; g < 2; ++g) {
    int i0 = (g * 1024 + tid) * 4;           // 16B-aligned vector offset
    if (i0 + 3 < n) {
      int4 r4 = *(const int4*)(rows + base + i0);
      int4 c4 = *(const int4*)(cols + base + i0);
      float4 v4 = *(const float4*)(vals + base + i0);
      int rr_[4] = {r4.x, r4.y, r4.z, r4.w};
      int cc_[4] = {c4.x, c4.y, c4.z, c4.w};
      float vv_[4] = {v4.x, v4.y, v4.z, v4.w};
#pragma unroll
      for (int j = 0; j < 4; ++j) {
        int e = g * 4 + j;
        ent[e] = make_uint2(__float_as_uint(vv_[j]),
                            ((unsigned)rr_[j] << 14) |
                                (unsigned)(cc_[j] + col_off));
        msk |= 1u << e;
        lp[e] = atomicAdd(&hist[rr_[j] >> 6], 1);
      }
    } else {
#pragma unroll
      for (int j = 0; j < 4; ++j) {
        int e = g * 4 + j, i = i0 + j;
        if (i < n) {
          int r = rows[base + i];
          int c = cols[base + i] + col_off;
          float v = vals[base + i];
          ent[e] = make_uint2(__float_as_uint(v),
                              ((unsigned)r << 14) | (unsigned)c);
          msk |= 1u << e;
          lp[e] = atomicAdd(&hist[r >> 6], 1);
        }
      }
    }
  }
  __syncthreads();

  int h = 0, v = 0;
  if (tid < NBK) {                           // waves 0,1 scan 128 bins
    h = hist[tid];
    v = h;
#pragma unroll
    for (int d = 1; d < 64; d <<= 1) {
      int t = __shfl_up(v, d);
      if (lane >= d) v += t;
    }
    if (lane == 63) wsum[wave] = v;
  }
  __syncthreads();
  if (tid < NBK) {
    int off = (wave == 1) ? wsum[0] : 0;
    lbase[tid] = off + v - h;
    gbase[tid] = h ? atomicAdd(&bcur[tid], h) : 0;
  }
  __syncthreads();
#pragma unroll
  for (int e = 0; e < 8; ++e) {
    if (msk & (1u << e)) {
      int b = (int)(ent[e].y >> 20);         // recompute bin from packed row
      stg[lbase[b] + lp[e]] = ent[e];
    }
  }
  __syncthreads();
  for (int i = tid; i < n; i += 1024) {
    uint2 ld = stg[i];
    int b = (int)(ld.y >> 20);
    int p = gbase[b] + (i - lbase[b]);
    if (p < CAP1B) e1[(size_t)b * CAP1B + p] = ld;
  }
}

// ---------------------------------------------------------------------------
// K2 (R15): sort-free fixed-point accumulation with 4-WAY REPLICATED
// accumulator. R14 PMC: 6.9M LDS conflict-cycles = 25% of pass2 runtime,
// dominated by same-address ds_add collisions (random rows, 16 slots/instr
// over 64 rows -> ~1.9 colliding pairs/instr). Copy = slot&3 -> collisions
// only within the same mod-4 slot class: expected pairs 1.875 -> 0.375.
// CPAD=1089 (64*17+1): +1 rotates bank mapping per copy. 17.4KB LDS still
// allows 4 blocks/CU x 8 waves = 32 waves/CU. Per 4-lane group: broadcast
// e1 entry, one 16B slice of the 64B srcT line, 4 mul + 4 rn-cvt + 4
// fire-and-forget ds_add. Readback sums the 4 copies (exact int adds) ->
// 1024 global unsafeAtomicAdd into z. Grid: (SB2, NBK), 512 threads.
__global__ __launch_bounds__(512, 8) void pass2_accum(
    const uint2* __restrict__ e1,
    const int* __restrict__ bcur,
    const float* __restrict__ srcT,     // [8320][16]
    float* __restrict__ z) {            // [N_RES][BATCH] (pre-zeroed)
  int bucket = blockIdx.y;
  int ch = blockIdx.x;
  int tid = threadIdx.x;

  int cnt = bcur[bucket];
  if (cnt > CAP1B) cnt = CAP1B;
  int base = ch * CHUNK2;
  if (base >= cnt) return;              // block-uniform early exit
  int n = cnt - base;
  if (n > CHUNK2) n = CHUNK2;

  __shared__ int acc[4 * CPAD];         // 17.4 KB, fixed-point 2^-16, 4 copies
  for (int i = tid; i < 4 * CPAD; i += 512) acc[i] = 0;
  __syncthreads();

  const uint2* __restrict__ src = e1 + (size_t)bucket * CAP1B + base;
  int wave = tid >> 6, lane = tid & 63;
  int g = lane >> 2;                    // entry slot within 16-entry step
  int bq = lane & 3;                    // batch quad
  int cbase = (g & 3) * CPAD + (bq << 2);  // copy base + batch-quad offset
  const float4* __restrict__ s4 = (const float4*)srcT;

  // Each wave owns a contiguous span; 2 entries per group per iteration
  // (2 independent chains), clamp+mask for the ragged end.
  int bw = wave * (CHUNK2 / 8);
  int lim = n - bw;
  if (lim > CHUNK2 / 8) lim = CHUNK2 / 8;
  for (int s = 0; s < lim; s += 32) {
    int i1 = bw + s + g;
    int i2 = bw + s + 16 + g;
    int c1 = (i1 < n) ? i1 : n - 1;
    int c2 = (i2 < n) ? i2 : n - 1;
    uint2 eA = src[c1];
    uint2 eB = src[c2];
    float4 sA = s4[(int)(eA.y & 16383u) * 4 + bq];
    float4 sB = s4[(int)(eB.y & 16383u) * 4 + bq];
    float vA = (i1 < n) ? __uint_as_float(eA.x) * 65536.f : 0.0f;
    float vB = (i2 < n) ? __uint_as_float(eB.x) * 65536.f : 0.0f;
    int aA = cbase + (int)((eA.y >> 14) & 63u) * 17;
    int aB = cbase + (int)((eB.y >> 14) & 63u) * 17;
    atomicAdd(&acc[aA + 0], __float2int_rn(vA * sA.x));
    atomicAdd(&acc[aA + 1], __float2int_rn(vA * sA.y));
    atomicAdd(&acc[aA + 2], __float2int_rn(vA * sA.z));
    atomicAdd(&acc[aA + 3], __float2int_rn(vA * sA.w));
    atomicAdd(&acc[aB + 0], __float2int_rn(vB * sB.x));
    atomicAdd(&acc[aB + 1], __float2int_rn(vB * sB.y));
    atomicAdd(&acc[aB + 2], __float2int_rn(vB * sB.z));
    atomicAdd(&acc[aB + 3], __float2int_rn(vB * sB.w));
  }
  __syncthreads();
  // Readback: sum 4 copies (exact int adds), convert, add into z.
  for (int i = tid; i < 64 * BATCH; i += 512) {
    int rr = i >> 4, b = i & 15;
    int o = rr * 17 + b;
    int sum = acc[o] + acc[CPAD + o] + acc[2 * CPAD + o] + acc[3 * CPAD + o];
    float fv = (float)sum * (1.0f / 65536.f);
    unsafeAtomicAdd(&z[(size_t)(bucket * 64 + rr) * BATCH + b], fv);
  }
}

// ---------------------------------------------------------------------------
__global__ __launch_bounds__(256) void finalize_z(
    const float* __restrict__ z, const float* __restrict__ state,
    const float* __restrict__ res_bias, const float* __restrict__ in_bias,
    float* __restrict__ out) {
  int tid = blockIdx.x * 256 + threadIdx.x;
  if (tid >= BATCH * N_RES) return;
  int b = tid >> 13;
  int r = tid & (N_RES - 1);
  float zz = z[r * 16 + b] + res_bias[r] + in_bias[r];
  out[tid] = (1.0f - LEAK) * state[tid] + LEAK * erff(zz);
}

// ---------------------------------------------------------------------------
// Fallback (small ws): atomic path, correct but slow.
__global__ __launch_bounds__(256) void transpose_nb(
    const float* __restrict__ state, const float* __restrict__ x,
    float* __restrict__ srcT) {
  int tid = blockIdx.x * 256 + threadIdx.x;
  if (tid < N_RES * BATCH) {
    int b = tid >> 13;
    int r = tid & (N_RES - 1);
    srcT[r * BATCH + b] = state[tid];
  }
  if (tid < N_IN * BATCH) {
    int b = tid >> 7;
    int c = tid & (N_IN - 1);
    srcT[(N_RES + c) * BATCH + b] = x[tid];
  }
}

__global__ __launch_bounds__(256) void spmm_atomic(
    const float* __restrict__ vals, const int* __restrict__ rows,
    const int* __restrict__ cols, const float* __restrict__ srcT,
    int col_off, float* __restrict__ zz, int nnz) {
  int i = blockIdx.x * blockDim.x + threadIdx.x;
  if (i >= nnz) return;
  float v = vals[i];
  int r = rows[i];
  int c = cols[i] + col_off;
  const float4* __restrict__ sp = (const float4*)(srcT + c * BATCH);
  float* zr = zz + r * BATCH;
#pragma unroll
  for (int qq = 0; qq < 4; ++qq) {
    float4 s = sp[qq];
    unsafeAtomicAdd(zr + qq * 4 + 0, v * s.x);
    unsafeAtomicAdd(zr + qq * 4 + 1, v * s.y);
    unsafeAtomicAdd(zr + qq * 4 + 2, v * s.z);
    unsafeAtomicAdd(zr + qq * 4 + 3, v * s.w);
  }
}

// ---------------------------------------------------------------------------
extern "C" void kernel_launch(void* const* d_in, const int* in_sizes, int n_in,
                              void* d_out, int out_size, void* d_ws, size_t ws_size,
                              hipStream_t stream) {
  const float* state    = (const float*)d_in[0];
  const float* x        = (const float*)d_in[1];
  const float* res_vals = (const float*)d_in[2];
  const int*   res_rows = (const int*)d_in[3];
  const int*   res_cols = (const int*)d_in[4];
  const float* res_bias = (const float*)d_in[5];
  const float* in_vals  = (const float*)d_in[6];
  const int*   in_rows  = (const int*)d_in[7];
  const int*   in_cols  = (const int*)d_in[8];
  const float* in_bias  = (const float*)d_in[9];

  const int res_nnz = in_sizes[2];
  const int in_nnz  = in_sizes[6];

  char* ws = (char*)d_ws;
  float* srcT = (float*)(ws + OFF_SRCT);
  float* z    = (float*)(ws + OFF_Z);
  float* out = (float*)d_out;

  if (ws_size >= REQ_A) {
    int* bcur = (int*)(ws + OFF_BCUR);
    uint2* e1 = (uint2*)(ws + OFF_E1);
    int nbres = (res_nnz + CHUNK1 - 1) / CHUNK1;
    int nbin  = (in_nnz + CHUNK1 - 1) / CHUNK1;
    int nchunks = nbres + nbin;

    hipMemsetAsync(bcur, 0, NBK * sizeof(int), stream);

    pass1_fused<<<nchunks + TBLK, 1024, 0, stream>>>(
        state, x, res_vals, res_rows, res_cols, res_nnz, nbres,
        in_vals, in_rows, in_cols, in_nnz, nchunks, srcT, z, e1, bcur);

    pass2_accum<<<dim3(SB2, NBK), 512, 0, stream>>>(e1, bcur, srcT, z);

    finalize_z<<<512, 256, 0, stream>>>(z, state, res_bias, in_bias, out);
  } else {
    hipMemsetAsync(z, 0, N_RES * BATCH * sizeof(float), stream);
    transpose_nb<<<512, 256, 0, stream>>>(state, x, srcT);
    spmm_atomic<<<(res_nnz + 255) / 256, 256, 0, stream>>>(
        res_vals, res_rows, res_cols, srcT, 0, z, res_nnz);
    spmm_atomic<<<(in_nnz + 255) / 256, 256, 0, stream>>>(
        in_vals, in_rows, in_cols, srcT, N_RES, z, in_nnz);
    finalize_z<<<512, 256, 0, stream>>>(z, state, res_bias, in_bias, out);
  }
}